// Round 3
// baseline (980.627 us; speedup 1.0000x reference)
//
#include <hip/hip_runtime.h>
#include <hip/hip_bf16.h>

#define BDIM 4
#define VDIM 20000
#define DDIM 64
#define RDIM 64
#define EDIM 200000
#define BV (BDIM*VDIM)
#define LN_EPS 1e-5f
#define NBB 250           // kvred blocks per batch
#define GMD 1000          // dense-kernel grid (16 rows/block-iter, 5 iters)

typedef __hip_bfloat16 bf16;

__device__ __forceinline__ float ldf(const float* p, size_t i){ return p[i]; }
__device__ __forceinline__ float ldf(const bf16* p, size_t i){ return __bfloat162float(p[i]); }
__device__ __forceinline__ void stf(float* p, size_t i, float v){ p[i] = v; }
__device__ __forceinline__ void stf(bf16* p, size_t i, float v){ p[i] = __float2bfloat16(v); }

__device__ __forceinline__ float dot4(float4 a, float4 b){
  return a.x*b.x + a.y*b.y + a.z*b.z + a.w*b.w;
}

// Wave-private LDS ordering: DS ops from one wave execute in order, so
// write->read of wave-private LDS needs no s_barrier; just fence compiler.
__device__ __forceinline__ void wsync(){
  __builtin_amdgcn_wave_barrier();
  __asm__ volatile("" ::: "memory");
}

// ---- diagnostic fill ----
__global__ void fill_kernel(float* __restrict__ out, float v, int n){
  int t = blockIdx.x * 256 + threadIdx.x;
  if (t < n) out[t] = v;
}

// ---- detect 64-bit index layout once ----
__global__ void detect_kernel(const int* __restrict__ ei_raw, int* __restrict__ flag){
  int tid = threadIdx.x;
  int nz = 0;
  for (int j = 2*tid + 1; j < 1024; j += 512) nz |= (ei_raw[j] != 0);
  nz = __any(nz);
  __shared__ int r[4];
  if ((tid & 63) == 0) r[tid >> 6] = nz;
  __syncthreads();
  if (tid == 0) flag[0] = (r[0] | r[1] | r[2] | r[3]) ? 0 : 1;   // 1 => 64-bit
}

__global__ void prep_idx_kernel(const int* __restrict__ ei_raw, const int* __restrict__ hi_raw,
                                const int* __restrict__ flag,
                                int* __restrict__ ei, int* __restrict__ hi){
  int is64 = flag[0];
  int t = blockIdx.x * 256 + threadIdx.x;
  if (t < 3*EDIM) ei[t] = is64 ? ei_raw[2*t] : ei_raw[t];
  if (t < BDIM)   hi[t] = is64 ? hi_raw[2*t] : hi_raw[t];
}

__global__ void zero_kernel(int* __restrict__ counts){
  int i = blockIdx.x * 256 + threadIdx.x;
  if (i < VDIM + 1) counts[i] = 0;
}

__global__ void count_kernel(const int* __restrict__ ei, int* __restrict__ counts){
  int e = blockIdx.x * 256 + threadIdx.x;
  if (e < EDIM){
    int dst = ei[e*3], rel = ei[e*3+1], src = ei[e*3+2];
    if ((unsigned)dst < VDIM && (unsigned)rel < RDIM && (unsigned)src < VDIM)
      atomicAdd(&counts[dst], 1);
  }
}

// ---- scan: per-thread segments + one wave scan, 1 barrier total ----
__global__ void scan_kernel(const int* __restrict__ counts, int* __restrict__ row_ptr, int* __restrict__ cursor){
  __shared__ int wsum[4];
  int tid = threadIdx.x, lane = tid & 63, wid = tid >> 6;
  const int SEG = (VDIM + 255) / 256;        // 79
  int lo = tid * SEG;
  int hi = lo + SEG; if (hi > VDIM) hi = VDIM;
  int s = 0;
  for (int i = lo; i < hi; i++) s += counts[i];
  int x = s;
  #pragma unroll
  for (int o = 1; o < 64; o <<= 1){
    int t = __shfl_up(x, o, 64);
    if (lane >= o) x += t;
  }
  if (lane == 63) wsum[wid] = x;
  __syncthreads();
  int wo = 0;
  for (int w = 0; w < wid; w++) wo += wsum[w];
  int run = wo + x - s;                      // exclusive prefix of this thread's segment
  for (int i = lo; i < hi; i++){
    row_ptr[i] = run; cursor[i] = run; run += counts[i];
  }
  if (tid == 255) row_ptr[VDIM] = run;       // total
}

__global__ void scatter_kernel(const int* __restrict__ ei, int* __restrict__ cursor,
                               int2* __restrict__ pk){
  int e = blockIdx.x * 256 + threadIdx.x;
  if (e < EDIM){
    int dst = ei[e*3], rel = ei[e*3+1], src = ei[e*3+2];
    if ((unsigned)dst < VDIM && (unsigned)rel < RDIM && (unsigned)src < VDIM){
      int p = atomicAdd(&cursor[dst], 1);
      pk[p] = make_int2(rel, src);
    }
  }
}

// ---- z projections (float4 weight reads) ----
__global__ void zcalc_kernel(const float* __restrict__ z,
                             const float* __restrict__ qkzw, const float* __restrict__ qkzb,
                             const float* __restrict__ vfw,  const float* __restrict__ vfb,
                             float* __restrict__ qk_z, float* __restrict__ zr){
  int idx = blockIdx.x * 256 + threadIdx.x;
  if (idx >= 49152) return;
  int which = idx >> 14;
  int r = idx & 16383;
  int b = r >> 12;
  int j = r & 4095;
  const float* wrow; float bias; float* outp;
  if (which == 0){ wrow = qkzw + (size_t)j*DDIM; bias = qkzb[j]; outp = qk_z; }
  else { int i = which - 1; wrow = vfw + (size_t)(i*4096 + j)*DDIM; bias = vfb[i*4096 + j]; outp = zr + i*16384; }
  const float4* zr4 = (const float4*)(z + (size_t)b*DDIM);
  const float4* wr4 = (const float4*)wrow;
  float acc = bias;
  #pragma unroll
  for (int i = 0; i < 16; i++) acc += dot4(zr4[i], wr4[i]);
  outp[r] = acc;
}

// ---- rspmm gather (CSR, packed idx), 8 vertices/block, 2 edges in flight ----
template<typename T>
__global__ __launch_bounds__(256) void rspmm_gather(
    const int* __restrict__ row_ptr, const int2* __restrict__ pk,
    const float* __restrict__ zrel, const T* __restrict__ X, T* __restrict__ out){
  int v0 = blockIdx.x * 8;
  int btch = threadIdx.x >> 6, d = threadIdx.x & 63;
  int rp[9];
  #pragma unroll
  for (int i = 0; i < 9; i++) rp[i] = row_ptr[v0 + i];
  const float* zb = zrel + btch*RDIM*DDIM + d;
  size_t xb = (size_t)btch*VDIM*64 + d;
  size_t ob = ((size_t)btch*VDIM + v0)*64 + d;
  #pragma unroll 1
  for (int vi = 0; vi < 8; vi++){
    int s = rp[vi], e = rp[vi+1];
    float acc0 = 0.f, acc1 = 0.f;
    int i = s;
    for (; i + 2 <= e; i += 2){
      int2 e0 = pk[i], e1 = pk[i+1];
      float x0 = ldf(X, xb + (size_t)e0.y*64);
      float x1 = ldf(X, xb + (size_t)e1.y*64);
      acc0 += zb[(size_t)e0.x*64] * x0;
      acc1 += zb[(size_t)e1.x*64] * x1;
    }
    if (i < e){
      int2 ed = pk[i];
      acc0 += zb[(size_t)ed.x*64] * ldf(X, xb + (size_t)ed.y*64);
    }
    stf(out, ob + (size_t)vi*64, acc0 + acc1);
  }
}

// ---- init qk_x: 4 rows/wave, weights in regs ----
template<typename T>
__global__ __launch_bounds__(256, 1) void init_qk_kernel(
    const float* __restrict__ x, const float* __restrict__ noise,
    const float* __restrict__ w1, const float* __restrict__ b1,
    const float* __restrict__ w2, const float* __restrict__ b2,
    T* __restrict__ out){
  __shared__ __align__(16) float tb[16*64];
  __shared__ __align__(16) float hb[16*64];
  int tid = threadIdx.x, lane = tid & 63, wid = tid >> 6;
  float w1a[64]; float4 w2r[16];
  #pragma unroll
  for (int i = 0; i < 64; i++) w1a[i] = w1[lane*65 + i];
  float wn = w1[lane*65 + 64];
  const float4* w2v = (const float4*)w2;
  #pragma unroll
  for (int i = 0; i < 16; i++) w2r[i] = w2v[lane*16 + i];
  float b1l = b1[lane], b2l = b2[lane];
  const float4* tbv = (const float4*)tb;
  const float4* hbv = (const float4*)hb;
  int tbase = wid*256 + lane;
  int fbase = wid*64;
  for (int r0 = blockIdx.x*16; r0 < BV; r0 += gridDim.x*16){
    int row0 = r0 + wid*4;
    size_t rb = (size_t)row0*64 + lane;
    float x0 = x[rb], x1 = x[rb+64], x2 = x[rb+128], x3 = x[rb+192];
    float n0 = noise[row0], n1 = noise[row0+1], n2 = noise[row0+2], n3 = noise[row0+3];
    tb[tbase] = x0; tb[tbase+64] = x1; tb[tbase+128] = x2; tb[tbase+192] = x3;
    wsync();
    float h0 = b1l + wn*n0, h1 = b1l + wn*n1, h2 = b1l + wn*n2, h3 = b1l + wn*n3;
    #pragma unroll
    for (int i4 = 0; i4 < 16; i4++){
      float4 t0 = tbv[fbase + i4],      t1 = tbv[fbase + 16 + i4];
      float4 t2 = tbv[fbase + 32 + i4], t3 = tbv[fbase + 48 + i4];
      float wa = w1a[i4*4+0], wb = w1a[i4*4+1], wc = w1a[i4*4+2], wd = w1a[i4*4+3];
      h0 += wa*t0.x + wb*t0.y + wc*t0.z + wd*t0.w;
      h1 += wa*t1.x + wb*t1.y + wc*t1.z + wd*t1.w;
      h2 += wa*t2.x + wb*t2.y + wc*t2.z + wd*t2.w;
      h3 += wa*t3.x + wb*t3.y + wc*t3.z + wd*t3.w;
    }
    hb[tbase]     = fmaxf(h0, 0.f);
    hb[tbase+64]  = fmaxf(h1, 0.f);
    hb[tbase+128] = fmaxf(h2, 0.f);
    hb[tbase+192] = fmaxf(h3, 0.f);
    wsync();
    float y0 = b2l, y1 = b2l, y2 = b2l, y3 = b2l;
    #pragma unroll
    for (int i4 = 0; i4 < 16; i4++){
      float4 w = w2r[i4];
      y0 += dot4(w, hbv[fbase + i4]);
      y1 += dot4(w, hbv[fbase + 16 + i4]);
      y2 += dot4(w, hbv[fbase + 32 + i4]);
      y3 += dot4(w, hbv[fbase + 48 + i4]);
    }
    stf(out, rb, y0); stf(out, rb+64, y1); stf(out, rb+128, y2); stf(out, rb+192, y3);
    wsync();
  }
}

// ---- init v_x: 4 rows/wave ----
template<typename T>
__global__ __launch_bounds__(256, 1) void init_v_kernel(
    const float* __restrict__ x, const int* __restrict__ h_index,
    const float* __restrict__ w1, const float* __restrict__ b1,
    const float* __restrict__ w2, const float* __restrict__ b2,
    T* __restrict__ out){
  __shared__ __align__(16) float tb[16*64];
  __shared__ __align__(16) float hb[16*64];
  int tid = threadIdx.x, lane = tid & 63, wid = tid >> 6;
  float4 w1r[16], w2r[16];
  const float4* w1v = (const float4*)w1;     // [64][128] -> row stride 32 float4
  const float4* w2v = (const float4*)w2;
  #pragma unroll
  for (int i = 0; i < 16; i++){ w1r[i] = w1v[lane*32 + i]; w2r[i] = w2v[lane*16 + i]; }
  float rsv = 0.f;
  #pragma unroll
  for (int i = 0; i < 16; i++){ float4 t = w1v[lane*32 + 16 + i]; rsv += t.x+t.y+t.z+t.w; }
  float b1l = b1[lane], b2l = b2[lane];
  int h0i = h_index[0], h1i = h_index[1], h2i = h_index[2], h3i = h_index[3];
  const float4* tbv = (const float4*)tb;
  const float4* hbv = (const float4*)hb;
  int tbase = wid*256 + lane;
  int fbase = wid*64;
  for (int r0 = blockIdx.x*16; r0 < BV; r0 += gridDim.x*16){
    int row0 = r0 + wid*4;
    int b = row0 / VDIM;                     // uniform within wave (16 | 20000)
    int vbase = row0 - b*VDIM;
    int hv = (b == 0) ? h0i : (b == 1) ? h1i : (b == 2) ? h2i : h3i;
    size_t rb = (size_t)row0*64 + lane;
    float x0 = x[rb], x1 = x[rb+64], x2 = x[rb+128], x3 = x[rb+192];
    tb[tbase] = x0; tb[tbase+64] = x1; tb[tbase+128] = x2; tb[tbase+192] = x3;
    wsync();
    float h0 = b1l + ((vbase   == hv) ? rsv : 0.f);
    float h1 = b1l + ((vbase+1 == hv) ? rsv : 0.f);
    float h2 = b1l + ((vbase+2 == hv) ? rsv : 0.f);
    float h3 = b1l + ((vbase+3 == hv) ? rsv : 0.f);
    #pragma unroll
    for (int i4 = 0; i4 < 16; i4++){
      float4 w = w1r[i4];
      h0 += dot4(w, tbv[fbase + i4]);
      h1 += dot4(w, tbv[fbase + 16 + i4]);
      h2 += dot4(w, tbv[fbase + 32 + i4]);
      h3 += dot4(w, tbv[fbase + 48 + i4]);
    }
    hb[tbase]     = fmaxf(h0, 0.f);
    hb[tbase+64]  = fmaxf(h1, 0.f);
    hb[tbase+128] = fmaxf(h2, 0.f);
    hb[tbase+192] = fmaxf(h3, 0.f);
    wsync();
    float y0 = b2l, y1 = b2l, y2 = b2l, y3 = b2l;
    #pragma unroll
    for (int i4 = 0; i4 < 16; i4++){
      float4 w = w2r[i4];
      y0 += dot4(w, hbv[fbase + i4]);
      y1 += dot4(w, hbv[fbase + 16 + i4]);
      y2 += dot4(w, hbv[fbase + 32 + i4]);
      y3 += dot4(w, hbv[fbase + 48 + i4]);
    }
    stf(out, rb, y0); stf(out, rb+64, y1); stf(out, rb+128, y2); stf(out, rb+192, y3);
    wsync();
  }
}

// ---- loop body: X = LN(mlp2(O + alpha*X))*ng + nb + X ; 4 rows/wave + prefetch ----
template<typename T>
__global__ __launch_bounds__(256, 1) void loop_body_kernel(
    const T* __restrict__ O, T* __restrict__ X,
    const float* __restrict__ alpha, const float* __restrict__ w1, const float* __restrict__ b1,
    const float* __restrict__ w2, const float* __restrict__ b2,
    const float* __restrict__ ng, const float* __restrict__ nb){
  __shared__ __align__(16) float tb[16*64];
  __shared__ __align__(16) float hb[16*64];
  int tid = threadIdx.x, lane = tid & 63, wid = tid >> 6;
  float4 w1r[16], w2r[16];
  const float4* w1v = (const float4*)w1;
  const float4* w2v = (const float4*)w2;
  #pragma unroll
  for (int i = 0; i < 16; i++){ w1r[i] = w1v[lane*16 + i]; w2r[i] = w2v[lane*16 + i]; }
  float all = alpha[lane], b1l = b1[lane], b2l = b2[lane];
  float ngl = ng[lane], nbl = nb[lane];
  const float4* tbv = (const float4*)tb;
  const float4* hbv = (const float4*)hb;
  int tbase = wid*256 + lane;
  int fbase = wid*64;
  const size_t end = (size_t)BV*64;
  const size_t stride = (size_t)gridDim.x*16*64;
  size_t rb = ((size_t)blockIdx.x*16 + wid*4)*64 + lane;
  float xs0 = ldf(X, rb),     ov0 = ldf(O, rb);
  float xs1 = ldf(X, rb+64),  ov1 = ldf(O, rb+64);
  float xs2 = ldf(X, rb+128), ov2 = ldf(O, rb+128);
  float xs3 = ldf(X, rb+192), ov3 = ldf(O, rb+192);
  for (; rb < end; rb += stride){
    size_t nrb = rb + stride;
    size_t prow = (nrb < end) ? nrb : rb;
    float nxs0 = ldf(X, prow),     nov0 = ldf(O, prow);
    float nxs1 = ldf(X, prow+64),  nov1 = ldf(O, prow+64);
    float nxs2 = ldf(X, prow+128), nov2 = ldf(O, prow+128);
    float nxs3 = ldf(X, prow+192), nov3 = ldf(O, prow+192);
    tb[tbase]     = ov0 + all*xs0;
    tb[tbase+64]  = ov1 + all*xs1;
    tb[tbase+128] = ov2 + all*xs2;
    tb[tbase+192] = ov3 + all*xs3;
    wsync();
    float h0=b1l, h1=b1l, h2=b1l, h3=b1l;
    #pragma unroll
    for (int i4 = 0; i4 < 16; i4++){
      float4 w = w1r[i4];
      h0 += dot4(w, tbv[fbase + i4]);
      h1 += dot4(w, tbv[fbase + 16 + i4]);
      h2 += dot4(w, tbv[fbase + 32 + i4]);
      h3 += dot4(w, tbv[fbase + 48 + i4]);
    }
    hb[tbase]     = fmaxf(h0, 0.f);
    hb[tbase+64]  = fmaxf(h1, 0.f);
    hb[tbase+128] = fmaxf(h2, 0.f);
    hb[tbase+192] = fmaxf(h3, 0.f);
    wsync();
    float y0=b2l, y1=b2l, y2=b2l, y3=b2l;
    #pragma unroll
    for (int i4 = 0; i4 < 16; i4++){
      float4 w = w2r[i4];
      y0 += dot4(w, hbv[fbase + i4]);
      y1 += dot4(w, hbv[fbase + 16 + i4]);
      y2 += dot4(w, hbv[fbase + 32 + i4]);
      y3 += dot4(w, hbv[fbase + 48 + i4]);
    }
    float s0=y0, s1=y1, s2=y2, s3=y3;
    float q0=y0*y0, q1=y1*y1, q2=y2*y2, q3=y3*y3;
    #pragma unroll
    for (int o = 32; o > 0; o >>= 1){
      s0 += __shfl_xor(s0,o,64); q0 += __shfl_xor(q0,o,64);
      s1 += __shfl_xor(s1,o,64); q1 += __shfl_xor(q1,o,64);
      s2 += __shfl_xor(s2,o,64); q2 += __shfl_xor(q2,o,64);
      s3 += __shfl_xor(s3,o,64); q3 += __shfl_xor(q3,o,64);
    }
    float mu, var;
    mu = s0*(1.f/64.f); var = fmaxf(q0*(1.f/64.f) - mu*mu, 0.f);
    stf(X, rb,     (y0-mu)*rsqrtf(var+LN_EPS)*ngl + nbl + xs0);
    mu = s1*(1.f/64.f); var = fmaxf(q1*(1.f/64.f) - mu*mu, 0.f);
    stf(X, rb+64,  (y1-mu)*rsqrtf(var+LN_EPS)*ngl + nbl + xs1);
    mu = s2*(1.f/64.f); var = fmaxf(q2*(1.f/64.f) - mu*mu, 0.f);
    stf(X, rb+128, (y2-mu)*rsqrtf(var+LN_EPS)*ngl + nbl + xs2);
    mu = s3*(1.f/64.f); var = fmaxf(q3*(1.f/64.f) - mu*mu, 0.f);
    stf(X, rb+192, (y3-mu)*rsqrtf(var+LN_EPS)*ngl + nbl + xs3);
    xs0=nxs0; ov0=nov0; xs1=nxs1; ov1=nov1;
    xs2=nxs2; ov2=nov2; xs3=nxs3; ov3=nov3;
    wsync();
  }
}

// ---- kvred: k-projection + kv/ksum/vsum partials (NO q work) ----
template<typename T>
__global__ __launch_bounds__(256, 2) void kvred_kernel(
    const T* __restrict__ Xqk, const T* __restrict__ Xv,
    const float* __restrict__ w, const float* __restrict__ bias,
    float* __restrict__ partial){
  __shared__ __align__(16) float tb[16*64];
  __shared__ __align__(16) float red[4*1152];
  int tid = threadIdx.x, lane = tid & 63, wid = tid >> 6;
  float4 wk[16];
  const float4* wv = (const float4*)w;
  #pragma unroll
  for (int i = 0; i < 16; i++) wk[i] = wv[(64+lane)*16 + i];
  float bk = bias[64+lane];
  int b = blockIdx.x / NBB, blk = blockIdx.x % NBB;
  float kv[16];
  #pragma unroll
  for (int i = 0; i < 16; i++) kv[i] = 0.f;
  float ks = 0.f, vs = 0.f;
  const float4* tbv = (const float4*)tb;
  int tbase = wid*256 + lane;
  int fbase = wid*64;
  int base = lane & 48;                      // h*16
  const int STEPS = VDIM / (NBB*16);         // 5
  size_t row = ((size_t)b*VDIM + blk*16 + wid*4)*64 + lane;
  const size_t rstride = (size_t)NBB*16*64;
  float x0 = ldf(Xqk, row),     x1 = ldf(Xqk, row+64);
  float x2 = ldf(Xqk, row+128), x3 = ldf(Xqk, row+192);
  float u0 = ldf(Xv, row),      u1 = ldf(Xv, row+64);
  float u2 = ldf(Xv, row+128),  u3 = ldf(Xv, row+192);
  for (int st = 0; st < STEPS; st++){
    size_t nrow = row + rstride;
    size_t prow = (st + 1 < STEPS) ? nrow : row;
    float nx0 = ldf(Xqk, prow),     nx1 = ldf(Xqk, prow+64);
    float nx2 = ldf(Xqk, prow+128), nx3 = ldf(Xqk, prow+192);
    float nu0 = ldf(Xv, prow),      nu1 = ldf(Xv, prow+64);
    float nu2 = ldf(Xv, prow+128),  nu3 = ldf(Xv, prow+192);
    tb[tbase] = x0; tb[tbase+64] = x1; tb[tbase+128] = x2; tb[tbase+192] = x3;
    wsync();
    float k0=bk, k1=bk, k2=bk, k3=bk;
    #pragma unroll
    for (int i4 = 0; i4 < 16; i4++){
      float4 wkc = wk[i4];
      k0 += dot4(wkc, tbv[fbase + i4]);
      k1 += dot4(wkc, tbv[fbase + 16 + i4]);
      k2 += dot4(wkc, tbv[fbase + 32 + i4]);
      k3 += dot4(wkc, tbv[fbase + 48 + i4]);
    }
    float c0=k0*k0, c1=k1*k1, c2=k2*k2, c3=k3*k3;
    #pragma unroll
    for (int o = 8; o > 0; o >>= 1){
      c0 += __shfl_xor(c0,o,64); c1 += __shfl_xor(c1,o,64);
      c2 += __shfl_xor(c2,o,64); c3 += __shfl_xor(c3,o,64);
    }
    k0 /= fmaxf(sqrtf(c0), 1e-12f); k1 /= fmaxf(sqrtf(c1), 1e-12f);
    k2 /= fmaxf(sqrtf(c2), 1e-12f); k3 /= fmaxf(sqrtf(c3), 1e-12f);
    ks += k0 + k1 + k2 + k3;
    vs += u0 + u1 + u2 + u3;
    #pragma unroll
    for (int dl = 0; dl < 16; dl++){
      kv[dl] += k0*__shfl(u0, base+dl, 64)
              + k1*__shfl(u1, base+dl, 64)
              + k2*__shfl(u2, base+dl, 64)
              + k3*__shfl(u3, base+dl, 64);
    }
    row = nrow;
    x0=nx0; x1=nx1; x2=nx2; x3=nx3;
    u0=nu0; u1=nu1; u2=nu2; u3=nu3;
    wsync();
  }
  // per-wave partials -> LDS -> block partial (coalesced)
  float* rw = red + wid*1152;
  #pragma unroll
  for (int dl = 0; dl < 16; dl++) rw[lane*16 + dl] = kv[dl];
  rw[1024 + lane] = ks;
  rw[1088 + lane] = vs;
  __syncthreads();
  float* P = partial + (size_t)blockIdx.x*1152;
  for (int j = tid; j < 1152; j += 256)
    P[j] = red[j] + red[1152+j] + red[2304+j] + red[3456+j];
}

// ---- reduce kvred partials ----
__global__ void qkred_kernel(const float* __restrict__ partial,
                             float* __restrict__ kvs, float* __restrict__ ksum, float* __restrict__ vsum){
  int b = blockIdx.x / 5, ch = blockIdx.x % 5;
  int j = ch*256 + threadIdx.x;
  if (j >= 1152) return;
  const float* P = partial + (size_t)b*NBB*1152;
  float s = 0.f;
  for (int t = 0; t < NBB; t++) s += P[(size_t)t*1152 + j];
  if (j < 1024)      kvs[b*1024 + j] = s;
  else if (j < 1088) ksum[b*64 + (j-1024)] = s;
  else               vsum[b*64 + (j-1088)] = s;
}

// ---- attention finalize: q-projection + head-norm + attention + LN ----
template<typename T>
__global__ __launch_bounds__(256, 2) void attn_final_kernel(
    const float* __restrict__ x, T* __restrict__ A, const T* __restrict__ Xv,
    const float* __restrict__ kvs, const float* __restrict__ ksum, const float* __restrict__ vsum,
    const float* __restrict__ w, const float* __restrict__ bias,
    const float* __restrict__ g, const float* __restrict__ bb){
  __shared__ float kvss[4096], kss[256], vss[256];
  __shared__ __align__(16) float tb[16*64];
  int tid = threadIdx.x, lane = tid & 63, wid = tid >> 6;
  float4 wq[16];
  const float4* wv = (const float4*)w;
  #pragma unroll
  for (int i = 0; i < 16; i++) wq[i] = wv[lane*16 + i];
  float bq = bias[lane];
  for (int i = tid; i < 4096; i += 256) kvss[i] = kvs[i];
  kss[tid] = ksum[tid];
  vss[tid] = vsum[tid];
  float gl = g[lane], bl = bb[lane];
  __syncthreads();
  int h16 = lane & 48, dl = lane & 15;
  const float4* tbv = (const float4*)tb;
  int tbase = wid*256 + lane;
  int fbase = wid*64;
  const size_t end = (size_t)BV*64;
  const size_t stride = (size_t)gridDim.x*16*64;
  size_t rb = ((size_t)blockIdx.x*16 + wid*4)*64 + lane;
  int rowi = blockIdx.x*16 + wid*4;
  float a0 = ldf(A, rb),      a1 = ldf(A, rb+64);
  float a2 = ldf(A, rb+128),  a3 = ldf(A, rb+192);
  float u0 = ldf(Xv, rb),     u1 = ldf(Xv, rb+64);
  float u2 = ldf(Xv, rb+128), u3 = ldf(Xv, rb+192);
  float xv0 = x[rb], xv1 = x[rb+64], xv2 = x[rb+128], xv3 = x[rb+192];
  for (; rb < end; rb += stride, rowi += gridDim.x*16){
    size_t nrb = rb + stride;
    size_t prow = (nrb < end) ? nrb : rb;
    float na0 = ldf(A, prow),      na1 = ldf(A, prow+64);
    float na2 = ldf(A, prow+128),  na3 = ldf(A, prow+192);
    float nu0 = ldf(Xv, prow),     nu1 = ldf(Xv, prow+64);
    float nu2 = ldf(Xv, prow+128), nu3 = ldf(Xv, prow+192);
    float nxv0 = x[prow], nxv1 = x[prow+64], nxv2 = x[prow+128], nxv3 = x[prow+192];
    int b = rowi / VDIM;                     // wave-uniform
    // q projection from staged Xqk row
    tb[tbase] = a0; tb[tbase+64] = a1; tb[tbase+128] = a2; tb[tbase+192] = a3;
    wsync();
    float q0=bq, q1=bq, q2=bq, q3=bq;
    #pragma unroll
    for (int i4 = 0; i4 < 16; i4++){
      float4 wqc = wq[i4];
      q0 += dot4(wqc, tbv[fbase + i4]);
      q1 += dot4(wqc, tbv[fbase + 16 + i4]);
      q2 += dot4(wqc, tbv[fbase + 32 + i4]);
      q3 += dot4(wqc, tbv[fbase + 48 + i4]);
    }
    float c0=q0*q0, c1=q1*q1, c2=q2*q2, c3=q3*q3;
    #pragma unroll
    for (int o = 8; o > 0; o >>= 1){
      c0 += __shfl_xor(c0,o,64); c1 += __shfl_xor(c1,o,64);
      c2 += __shfl_xor(c2,o,64); c3 += __shfl_xor(c3,o,64);
    }
    q0 /= fmaxf(sqrtf(c0), 1e-12f); q1 /= fmaxf(sqrtf(c1), 1e-12f);
    q2 /= fmaxf(sqrtf(c2), 1e-12f); q3 /= fmaxf(sqrtf(c3), 1e-12f);
    // attention
    float vsb = vss[b*64+lane];
    float num0 = vsb + u0*(float)VDIM, num1 = vsb + u1*(float)VDIM;
    float num2 = vsb + u2*(float)VDIM, num3 = vsb + u3*(float)VDIM;
    float den0 = 2.0f*(float)VDIM, den1 = den0, den2 = den0, den3 = den0;
    int kbase = b*1024 + h16*16 + dl;
    int ksbase = b*64 + h16;
    #pragma unroll
    for (int j = 0; j < 16; j++){
      float kvj = kvss[kbase + j*16];
      float ksj = kss[ksbase + j];
      float qj0 = __shfl(q0, h16 + j, 64);
      float qj1 = __shfl(q1, h16 + j, 64);
      float qj2 = __shfl(q2, h16 + j, 64);
      float qj3 = __shfl(q3, h16 + j, 64);
      num0 += qj0*kvj; den0 += qj0*ksj;
      num1 += qj1*kvj; den1 += qj1*ksj;
      num2 += qj2*kvj; den2 += qj2*ksj;
      num3 += qj3*kvj; den3 += qj3*ksj;
    }
    float y0 = xv0 + num0/den0, y1 = xv1 + num1/den1;
    float y2 = xv2 + num2/den2, y3 = xv3 + num3/den3;
    float s0=y0, s1=y1, s2=y2, s3=y3;
    float t0=y0*y0, t1=y1*y1, t2=y2*y2, t3=y3*y3;
    #pragma unroll
    for (int o = 32; o > 0; o >>= 1){
      s0 += __shfl_xor(s0,o,64); t0 += __shfl_xor(t0,o,64);
      s1 += __shfl_xor(s1,o,64); t1 += __shfl_xor(t1,o,64);
      s2 += __shfl_xor(s2,o,64); t2 += __shfl_xor(t2,o,64);
      s3 += __shfl_xor(s3,o,64); t3 += __shfl_xor(t3,o,64);
    }
    float mu, var;
    mu = s0*(1.f/64.f); var = fmaxf(t0*(1.f/64.f) - mu*mu, 0.f);
    stf(A, rb,     (y0-mu)*rsqrtf(var+LN_EPS)*gl + bl);
    mu = s1*(1.f/64.f); var = fmaxf(t1*(1.f/64.f) - mu*mu, 0.f);
    stf(A, rb+64,  (y1-mu)*rsqrtf(var+LN_EPS)*gl + bl);
    mu = s2*(1.f/64.f); var = fmaxf(t2*(1.f/64.f) - mu*mu, 0.f);
    stf(A, rb+128, (y2-mu)*rsqrtf(var+LN_EPS)*gl + bl);
    mu = s3*(1.f/64.f); var = fmaxf(t3*(1.f/64.f) - mu*mu, 0.f);
    stf(A, rb+192, (y3-mu)*rsqrtf(var+LN_EPS)*gl + bl);
    a0=na0; a1=na1; a2=na2; a3=na3;
    u0=nu0; u1=nu1; u2=nu2; u3=nu3;
    xv0=nxv0; xv1=nxv1; xv2=nxv2; xv3=nxv3;
    wsync();
  }
}

// ---- final FFN + LN -> fp32 out: 4 rows/wave ----
template<typename T>
__global__ __launch_bounds__(256, 1) void final_kernel(
    const T* __restrict__ X1,
    const float* __restrict__ w1, const float* __restrict__ b1,
    const float* __restrict__ w2, const float* __restrict__ b2,
    const float* __restrict__ g, const float* __restrict__ bb,
    float* __restrict__ out){
  __shared__ __align__(16) float tb[16*64];
  __shared__ __align__(16) float hb[16*64];
  int tid = threadIdx.x, lane = tid & 63, wid = tid >> 6;
  float4 w1r[16], w2r[16];
  const float4* w1v = (const float4*)w1;
  const float4* w2v = (const float4*)w2;
  #pragma unroll
  for (int i = 0; i < 16; i++){ w1r[i] = w1v[lane*16 + i]; w2r[i] = w2v[lane*16 + i]; }
  float b1l = b1[lane], b2l = b2[lane], gl = g[lane], bl = bb[lane];
  const float4* tbv = (const float4*)tb;
  const float4* hbv = (const float4*)hb;
  int tbase = wid*256 + lane;
  int fbase = wid*64;
  for (int r0 = blockIdx.x*16; r0 < BV; r0 += gridDim.x*16){
    size_t rb = ((size_t)r0 + wid*4)*64 + lane;
    float x0 = ldf(X1, rb),     x1 = ldf(X1, rb+64);
    float x2 = ldf(X1, rb+128), x3 = ldf(X1, rb+192);
    tb[tbase] = x0; tb[tbase+64] = x1; tb[tbase+128] = x2; tb[tbase+192] = x3;
    wsync();
    float h0=b1l, h1=b1l, h2=b1l, h3=b1l;
    #pragma unroll
    for (int i4 = 0; i4 < 16; i4++){
      float4 w = w1r[i4];
      h0 += dot4(w, tbv[fbase + i4]);
      h1 += dot4(w, tbv[fbase + 16 + i4]);
      h2 += dot4(w, tbv[fbase + 32 + i4]);
      h3 += dot4(w, tbv[fbase + 48 + i4]);
    }
    hb[tbase]     = fmaxf(h0, 0.f);
    hb[tbase+64]  = fmaxf(h1, 0.f);
    hb[tbase+128] = fmaxf(h2, 0.f);
    hb[tbase+192] = fmaxf(h3, 0.f);
    wsync();
    float y0=b2l, y1=b2l, y2=b2l, y3=b2l;
    #pragma unroll
    for (int i4 = 0; i4 < 16; i4++){
      float4 w = w2r[i4];
      y0 += dot4(w, hbv[fbase + i4]);
      y1 += dot4(w, hbv[fbase + 16 + i4]);
      y2 += dot4(w, hbv[fbase + 32 + i4]);
      y3 += dot4(w, hbv[fbase + 48 + i4]);
    }
    float t0 = x0 + y0, t1 = x1 + y1, t2 = x2 + y2, t3 = x3 + y3;
    float s0=t0, s1=t1, s2=t2, s3=t3;
    float q0=t0*t0, q1=t1*t1, q2=t2*t2, q3=t3*t3;
    #pragma unroll
    for (int o = 32; o > 0; o >>= 1){
      s0 += __shfl_xor(s0,o,64); q0 += __shfl_xor(q0,o,64);
      s1 += __shfl_xor(s1,o,64); q1 += __shfl_xor(q1,o,64);
      s2 += __shfl_xor(s2,o,64); q2 += __shfl_xor(q2,o,64);
      s3 += __shfl_xor(s3,o,64); q3 += __shfl_xor(q3,o,64);
    }
    float mu, var;
    mu = s0*(1.f/64.f); var = fmaxf(q0*(1.f/64.f) - mu*mu, 0.f);
    out[rb]     = (t0-mu)*rsqrtf(var+LN_EPS)*gl + bl;
    mu = s1*(1.f/64.f); var = fmaxf(q1*(1.f/64.f) - mu*mu, 0.f);
    out[rb+64]  = (t1-mu)*rsqrtf(var+LN_EPS)*gl + bl;
    mu = s2*(1.f/64.f); var = fmaxf(q2*(1.f/64.f) - mu*mu, 0.f);
    out[rb+128] = (t2-mu)*rsqrtf(var+LN_EPS)*gl + bl;
    mu = s3*(1.f/64.f); var = fmaxf(q3*(1.f/64.f) - mu*mu, 0.f);
    out[rb+192] = (t3-mu)*rsqrtf(var+LN_EPS)*gl + bl;
    wsync();
  }
}

// ================= host side =================
static const int DICT_SIZES[42] = {
  5120000,256,256,80000,262144,4096,4160,64,4096,64,
  8192,64,4096,64,8192,128,8192,128,8192,128,
  128,128,128,524288,8192,8192,128,8192,128,128,
  128,128,4096,64,4096,64,64,64,64,64,
  4,600000};

template<typename T>
static void run_pipeline(const float* const* N, const int* hi,
                         const int* row_ptr, const int2* pk,
                         float* qk_z, float* zr, float* kvs, float* part,
                         T* Obuf, T* A, T* B, float* outp, hipStream_t stream){
  float* ksum = kvs + 4096;
  float* vsum = kvs + 4352;

  zcalc_kernel<<<192, 256, 0, stream>>>(N[1], N[4], N[5], N[23], N[24], qk_z, zr);

  init_qk_kernel<T><<<GMD, 256, 0, stream>>>(N[0], N[3], N[6], N[7], N[8], N[9], A);
  for (int i = 0; i < 2; i++){
    rspmm_gather<T><<<VDIM/8, 256, 0, stream>>>(row_ptr, pk, qk_z, A, Obuf);
    loop_body_kernel<T><<<GMD, 256, 0, stream>>>(Obuf, A, N[20] + i*64, N[16] + i*4096, N[17] + i*64,
                                                 N[18] + i*4096, N[19] + i*64, N[21] + i*64, N[22] + i*64);
  }
  init_v_kernel<T><<<GMD, 256, 0, stream>>>(N[0], hi, N[10], N[11], N[12], N[13], B);
  for (int i = 0; i < 2; i++){
    rspmm_gather<T><<<VDIM/8, 256, 0, stream>>>(row_ptr, pk, zr + i*16384, B, Obuf);
    loop_body_kernel<T><<<GMD, 256, 0, stream>>>(Obuf, B, N[29] + i*64, N[25] + i*4096, N[26] + i*64,
                                                 N[27] + i*4096, N[28] + i*64, N[30] + i*64, N[31] + i*64);
  }
  kvred_kernel<T><<<BDIM*NBB, 256, 0, stream>>>(A, B, N[14], N[15], part);
  qkred_kernel<<<20, 256, 0, stream>>>(part, kvs, ksum, vsum);
  attn_final_kernel<T><<<GMD, 256, 0, stream>>>(N[0], A, B, kvs, ksum, vsum, N[14], N[15], N[36], N[37]);
  final_kernel<T><<<GMD, 256, 0, stream>>>(A, N[32], N[33], N[34], N[35], N[38], N[39], outp);
}

extern "C" void kernel_launch(void* const* d_in, const int* in_sizes, int n_in,
                              void* d_out, int out_size, void* d_ws, size_t ws_size,
                              hipStream_t stream){
  float* outp = (float*)d_out;
  const int GOUT = (out_size + 255) / 256;

  if (n_in != 42){
    fill_kernel<<<GOUT, 256, 0, stream>>>(outp, 2000.0f + (float)n_in, out_size);
    return;
  }
  auto sz_ok = [&](int s, int e)->bool{
    if (s == e) return true;
    if ((e == 4 || e == 600000) && s == 2*e) return true;
    return false;
  };
  int bad = -1;
  for (int i = 0; i < 42 && bad < 0; i++)
    if (!sz_ok(in_sizes[i], DICT_SIZES[i])) bad = i;
  if (bad >= 0){
    fill_kernel<<<GOUT, 256, 0, stream>>>(outp, 1000.0f + (float)bad, out_size);
    return;
  }

  const float* N[40];
  for (int i = 0; i < 40; i++) N[i] = (const float*)d_in[i];
  const int* hi_raw = (const int*)d_in[40];
  const int* ei_raw = (const int*)d_in[41];

  char* p = (char*)d_ws;
  auto alloc = [&](size_t bytes)->char*{ char* r = p; p += (bytes + 255) / 256 * 256; return r; };
  int* ei      = (int*)alloc((size_t)3*EDIM*4);
  int* hi      = (int*)alloc(256);
  int* eflag   = (int*)alloc(256);
  int* counts  = (int*)alloc((VDIM+1)*4);
  int* row_ptr = (int*)alloc((VDIM+1)*4);
  int* cursor  = (int*)alloc((VDIM+1)*4);
  int2* pk     = (int2*)alloc((size_t)EDIM*8);
  float* qk_z  = (float*)alloc(16384u*4);
  float* zr    = (float*)alloc(32768u*4);
  float* kvs   = (float*)alloc(4608u*4);
  float* part  = (float*)alloc((size_t)BDIM*NBB*1152*4);
  size_t fixed = (size_t)(p - (char*)d_ws);
  bool f32ok = ws_size >= fixed + 3*(size_t)BV*64*4 + 1024;

  detect_kernel<<<1, 256, 0, stream>>>(ei_raw, eflag);
  prep_idx_kernel<<<(3*EDIM+255)/256, 256, 0, stream>>>(ei_raw, hi_raw, eflag, ei, hi);
  zero_kernel<<<(VDIM+256)/256, 256, 0, stream>>>(counts);
  count_kernel<<<(EDIM+255)/256, 256, 0, stream>>>(ei, counts);
  scan_kernel<<<1, 256, 0, stream>>>(counts, row_ptr, cursor);
  scatter_kernel<<<(EDIM+255)/256, 256, 0, stream>>>(ei, cursor, pk);

  if (f32ok){
    float* Obuf = (float*)alloc((size_t)BV*64*4);
    float* A    = (float*)alloc((size_t)BV*64*4);
    float* B    = (float*)alloc((size_t)BV*64*4);
    run_pipeline<float>(N, hi, row_ptr, pk, qk_z, zr, kvs, part, Obuf, A, B, outp, stream);
  } else {
    bf16* Obuf = (bf16*)alloc((size_t)BV*64*2);
    bf16* A    = (bf16*)alloc((size_t)BV*64*2);
    bf16* B    = (bf16*)alloc((size_t)BV*64*2);
    run_pipeline<bf16>(N, hi, row_ptr, pk, qk_z, zr, kvs, part, Obuf, A, B, outp, stream);
  }
}

// Round 4
// 751.230 us; speedup vs baseline: 1.3054x; 1.3054x over previous
//
#include <hip/hip_runtime.h>
#include <hip/hip_bf16.h>

#define BDIM 4
#define VDIM 20000
#define DDIM 64
#define RDIM 64
#define EDIM 200000
#define BV (BDIM*VDIM)
#define LN_EPS 1e-5f
#define NBB 250           // kvred blocks per batch
#define GMD 1000          // attn_final grid
#define NTILE 1250        // BV/64 row-tiles for MFMA kernels

typedef __hip_bfloat16 bf16;
typedef __attribute__((ext_vector_type(8))) short short8v;
typedef __attribute__((ext_vector_type(4))) float floatx4;

__device__ __forceinline__ float ldf(const float* p, size_t i){ return p[i]; }
__device__ __forceinline__ float ldf(const bf16* p, size_t i){ return __bfloat162float(p[i]); }
__device__ __forceinline__ void stf(float* p, size_t i, float v){ p[i] = v; }
__device__ __forceinline__ void stf(bf16* p, size_t i, float v){ p[i] = __float2bfloat16(v); }

__device__ __forceinline__ unsigned short f2b(float f){
  unsigned u = __builtin_bit_cast(unsigned, f);
  u += 0x7fffu + ((u >> 16) & 1u);
  return (unsigned short)(u >> 16);
}
__device__ __forceinline__ float b2f(unsigned short h){
  unsigned u = ((unsigned)h) << 16;
  return __builtin_bit_cast(float, u);
}
__device__ __forceinline__ float4 ldf4(const float* p, size_t i){ return *(const float4*)(p+i); }
__device__ __forceinline__ float4 ldf4(const bf16* p, size_t i){
  ushort4 u = *(const ushort4*)(p+i);
  return make_float4(b2f(u.x), b2f(u.y), b2f(u.z), b2f(u.w));
}
// LDS tile swizzle: element index for [16][64] bf16 tile, 16B-unit XOR on row
__device__ __forceinline__ int swz(int r, int c){ return r*64 + (c ^ ((r & 7) << 3)); }

__device__ __forceinline__ float dot4(float4 a, float4 b){
  return a.x*b.x + a.y*b.y + a.z*b.z + a.w*b.w;
}

// Wave-private LDS ordering: DS ops from one wave execute in order; just fence compiler.
__device__ __forceinline__ void wsync(){
  __builtin_amdgcn_wave_barrier();
  __asm__ volatile("" ::: "memory");
}

// ---- diagnostic fill ----
__global__ void fill_kernel(float* __restrict__ out, float v, int n){
  int t = blockIdx.x * 256 + threadIdx.x;
  if (t < n) out[t] = v;
}

// ---- detect 64-bit index layout once ----
__global__ void detect_kernel(const int* __restrict__ ei_raw, int* __restrict__ flag){
  int tid = threadIdx.x;
  int nz = 0;
  for (int j = 2*tid + 1; j < 1024; j += 512) nz |= (ei_raw[j] != 0);
  nz = __any(nz);
  __shared__ int r[4];
  if ((tid & 63) == 0) r[tid >> 6] = nz;
  __syncthreads();
  if (tid == 0) flag[0] = (r[0] | r[1] | r[2] | r[3]) ? 0 : 1;   // 1 => 64-bit
}

__global__ void prep_idx_kernel(const int* __restrict__ ei_raw, const int* __restrict__ hi_raw,
                                const int* __restrict__ flag,
                                int* __restrict__ ei, int* __restrict__ hi){
  int is64 = flag[0];
  int t = blockIdx.x * 256 + threadIdx.x;
  if (t < 3*EDIM) ei[t] = is64 ? ei_raw[2*t] : ei_raw[t];
  if (t < BDIM)   hi[t] = is64 ? hi_raw[2*t] : hi_raw[t];
}

__global__ void zero_kernel(int* __restrict__ counts){
  int i = blockIdx.x * 256 + threadIdx.x;
  if (i < VDIM + 1) counts[i] = 0;
}

__global__ void count_kernel(const int* __restrict__ ei, int* __restrict__ counts){
  int e = blockIdx.x * 256 + threadIdx.x;
  if (e < EDIM){
    int dst = ei[e*3], rel = ei[e*3+1], src = ei[e*3+2];
    if ((unsigned)dst < VDIM && (unsigned)rel < RDIM && (unsigned)src < VDIM)
      atomicAdd(&counts[dst], 1);
  }
}

// ---- scan: per-thread segments + one wave scan, 1 barrier total ----
__global__ void scan_kernel(const int* __restrict__ counts, int* __restrict__ row_ptr, int* __restrict__ cursor){
  __shared__ int wsum[4];
  int tid = threadIdx.x, lane = tid & 63, wid = tid >> 6;
  const int SEG = (VDIM + 255) / 256;        // 79
  int lo = tid * SEG;
  int hi = lo + SEG; if (hi > VDIM) hi = VDIM;
  int s = 0;
  for (int i = lo; i < hi; i++) s += counts[i];
  int x = s;
  #pragma unroll
  for (int o = 1; o < 64; o <<= 1){
    int t = __shfl_up(x, o, 64);
    if (lane >= o) x += t;
  }
  if (lane == 63) wsum[wid] = x;
  __syncthreads();
  int wo = 0;
  for (int w = 0; w < wid; w++) wo += wsum[w];
  int run = wo + x - s;                      // exclusive prefix of this thread's segment
  for (int i = lo; i < hi; i++){
    row_ptr[i] = run; cursor[i] = run; run += counts[i];
  }
  if (tid == 255) row_ptr[VDIM] = run;       // total
}

__global__ void scatter_kernel(const int* __restrict__ ei, int* __restrict__ cursor,
                               int2* __restrict__ pk){
  int e = blockIdx.x * 256 + threadIdx.x;
  if (e < EDIM){
    int dst = ei[e*3], rel = ei[e*3+1], src = ei[e*3+2];
    if ((unsigned)dst < VDIM && (unsigned)rel < RDIM && (unsigned)src < VDIM){
      int p = atomicAdd(&cursor[dst], 1);
      pk[p] = make_int2(rel, src);
    }
  }
}

// ---- z projections (float4 weight reads) ----
__global__ void zcalc_kernel(const float* __restrict__ z,
                             const float* __restrict__ qkzw, const float* __restrict__ qkzb,
                             const float* __restrict__ vfw,  const float* __restrict__ vfb,
                             float* __restrict__ qk_z, float* __restrict__ zr){
  int idx = blockIdx.x * 256 + threadIdx.x;
  if (idx >= 49152) return;
  int which = idx >> 14;
  int r = idx & 16383;
  int b = r >> 12;
  int j = r & 4095;
  const float* wrow; float bias; float* outp;
  if (which == 0){ wrow = qkzw + (size_t)j*DDIM; bias = qkzb[j]; outp = qk_z; }
  else { int i = which - 1; wrow = vfw + (size_t)(i*4096 + j)*DDIM; bias = vfb[i*4096 + j]; outp = zr + i*16384; }
  const float4* zr4 = (const float4*)(z + (size_t)b*DDIM);
  const float4* wr4 = (const float4*)wrow;
  float acc = bias;
  #pragma unroll
  for (int i = 0; i < 16; i++) acc += dot4(zr4[i], wr4[i]);
  outp[r] = acc;
}

// ---- rspmm gather (CSR, packed idx), 8 vertices/block, 2 edges in flight ----
template<typename T>
__global__ __launch_bounds__(256) void rspmm_gather(
    const int* __restrict__ row_ptr, const int2* __restrict__ pk,
    const float* __restrict__ zrel, const T* __restrict__ X, T* __restrict__ out){
  int v0 = blockIdx.x * 8;
  int btch = threadIdx.x >> 6, d = threadIdx.x & 63;
  int rp[9];
  #pragma unroll
  for (int i = 0; i < 9; i++) rp[i] = row_ptr[v0 + i];
  const float* zb = zrel + btch*RDIM*DDIM + d;
  size_t xb = (size_t)btch*VDIM*64 + d;
  size_t ob = ((size_t)btch*VDIM + v0)*64 + d;
  #pragma unroll 1
  for (int vi = 0; vi < 8; vi++){
    int s = rp[vi], e = rp[vi+1];
    float acc0 = 0.f, acc1 = 0.f;
    int i = s;
    for (; i + 2 <= e; i += 2){
      int2 e0 = pk[i], e1 = pk[i+1];
      float x0 = ldf(X, xb + (size_t)e0.y*64);
      float x1 = ldf(X, xb + (size_t)e1.y*64);
      acc0 += zb[(size_t)e0.x*64] * x0;
      acc1 += zb[(size_t)e1.x*64] * x1;
    }
    if (i < e){
      int2 ed = pk[i];
      acc0 += zb[(size_t)ed.x*64] * ldf(X, xb + (size_t)ed.y*64);
    }
    stf(out, ob + (size_t)vi*64, acc0 + acc1);
  }
}

// ================= MFMA dense kernels =================
// Per wave: 16-row x 64-col tile. A-frag: lane holds row (lane&15), k-slice (lane>>4).
// B-frag (weights): lane holds W[col=(lane&15)+16nt][k-slice]. C/D: col=lane&15,
// row=(lane>>4)*4+q (m89-verified). LDS tiles [16][64] bf16 with row-XOR swizzle.

// ---- loop body: X = LN(mlp2(O + alpha*X))*ng + nb + X ----
template<typename T>
__global__ __launch_bounds__(256) void loop_mfma_kernel(
    const T* __restrict__ O, T* __restrict__ X,
    const float* __restrict__ alpha, const float* __restrict__ w1, const float* __restrict__ b1,
    const float* __restrict__ w2, const float* __restrict__ b2,
    const float* __restrict__ ng, const float* __restrict__ nb){
  __shared__ unsigned short Tl[4][1024];
  __shared__ unsigned short Xl[4][1024];
  __shared__ unsigned short Hl[4][1024];
  int tid = threadIdx.x, lane = tid & 63, wid = tid >> 6;
  int lr = lane & 15, lg = lane >> 4;
  short8v w1f[4][2], w2f[4][2];
  #pragma unroll
  for (int nt = 0; nt < 4; nt++){
    int col = lr + 16*nt;
    #pragma unroll
    for (int ks = 0; ks < 2; ks++){
      const float* p1 = w1 + col*64 + ks*32 + lg*8;
      const float* p2 = w2 + col*64 + ks*32 + lg*8;
      short8v f, g;
      #pragma unroll
      for (int j = 0; j < 8; j++){ f[j] = (short)f2b(p1[j]); g[j] = (short)f2b(p2[j]); }
      w1f[nt][ks] = f; w2f[nt][ks] = g;
    }
  }
  float4 al = ((const float4*)alpha)[lr];
  float b1l[4], b2l[4], ngl[4], nbl[4];
  #pragma unroll
  for (int nt = 0; nt < 4; nt++){
    int c = lr + 16*nt;
    b1l[nt] = b1[c]; b2l[nt] = b2[c]; ngl[nt] = ng[c]; nbl[nt] = nb[c];
  }
  unsigned short* Tw = Tl[wid];
  unsigned short* Xw = Xl[wid];
  unsigned short* Hw = Hl[wid];
  floatx4 zz = {0.f, 0.f, 0.f, 0.f};
  for (int tile = blockIdx.x; tile < NTILE; tile += gridDim.x){
    int row0 = tile*64 + wid*16;
    #pragma unroll
    for (int it = 0; it < 4; it++){
      int rl = it*4 + lg;
      size_t gi = (size_t)(row0 + rl)*64 + 4*lr;
      float4 xs4 = ldf4(X, gi);
      float4 ov4 = ldf4(O, gi);
      int si = swz(rl, 4*lr);
      ushort4 tt;
      tt.x = f2b(ov4.x + al.x*xs4.x);
      tt.y = f2b(ov4.y + al.y*xs4.y);
      tt.z = f2b(ov4.z + al.z*xs4.z);
      tt.w = f2b(ov4.w + al.w*xs4.w);
      *(ushort4*)&Tw[si] = tt;
      ushort4 xx;
      xx.x = f2b(xs4.x); xx.y = f2b(xs4.y); xx.z = f2b(xs4.z); xx.w = f2b(xs4.w);
      *(ushort4*)&Xw[si] = xx;
    }
    wsync();
    short8v a0 = *(const short8v*)&Tw[swz(lr, lg*8)];
    short8v a1 = *(const short8v*)&Tw[swz(lr, 32 + lg*8)];
    #pragma unroll
    for (int nt = 0; nt < 4; nt++){
      floatx4 acc = zz;
      acc = __builtin_amdgcn_mfma_f32_16x16x32_bf16(a0, w1f[nt][0], acc, 0, 0, 0);
      acc = __builtin_amdgcn_mfma_f32_16x16x32_bf16(a1, w1f[nt][1], acc, 0, 0, 0);
      #pragma unroll
      for (int q = 0; q < 4; q++)
        Hw[swz(lg*4 + q, lr + 16*nt)] = f2b(fmaxf(acc[q] + b1l[nt], 0.f));
    }
    wsync();
    short8v h0 = *(const short8v*)&Hw[swz(lr, lg*8)];
    short8v h1 = *(const short8v*)&Hw[swz(lr, 32 + lg*8)];
    float y[4][4];
    float s[4] = {0.f,0.f,0.f,0.f}, ss[4] = {0.f,0.f,0.f,0.f};
    #pragma unroll
    for (int nt = 0; nt < 4; nt++){
      floatx4 acc = zz;
      acc = __builtin_amdgcn_mfma_f32_16x16x32_bf16(h0, w2f[nt][0], acc, 0, 0, 0);
      acc = __builtin_amdgcn_mfma_f32_16x16x32_bf16(h1, w2f[nt][1], acc, 0, 0, 0);
      #pragma unroll
      for (int q = 0; q < 4; q++){
        float v = acc[q] + b2l[nt];
        y[nt][q] = v; s[q] += v; ss[q] += v*v;
      }
    }
    #pragma unroll
    for (int o = 1; o < 16; o <<= 1){
      #pragma unroll
      for (int q = 0; q < 4; q++){
        s[q] += __shfl_xor(s[q], o, 64);
        ss[q] += __shfl_xor(ss[q], o, 64);
      }
    }
    float mu[4], rs[4];
    #pragma unroll
    for (int q = 0; q < 4; q++){
      mu[q] = s[q]*(1.f/64.f);
      float var = fmaxf(ss[q]*(1.f/64.f) - mu[q]*mu[q], 0.f);
      rs[q] = rsqrtf(var + LN_EPS);
    }
    #pragma unroll
    for (int nt = 0; nt < 4; nt++){
      #pragma unroll
      for (int q = 0; q < 4; q++){
        int rl = lg*4 + q, c = lr + 16*nt;
        float xs = b2f(Xw[swz(rl, c)]);
        float v = (y[nt][q] - mu[q])*rs[q]*ngl[nt] + nbl[nt] + xs;
        stf(X, (size_t)(row0 + rl)*64 + c, v);
      }
    }
    wsync();
  }
}

// ---- final: out = LN(X1 + mlp2(X1))*g + b  (fp32 out) ----
template<typename T>
__global__ __launch_bounds__(256) void final_mfma_kernel(
    const T* __restrict__ X1,
    const float* __restrict__ w1, const float* __restrict__ b1,
    const float* __restrict__ w2, const float* __restrict__ b2,
    const float* __restrict__ g, const float* __restrict__ bb,
    float* __restrict__ out){
  __shared__ unsigned short Tl[4][1024];
  __shared__ unsigned short Hl[4][1024];
  int tid = threadIdx.x, lane = tid & 63, wid = tid >> 6;
  int lr = lane & 15, lg = lane >> 4;
  short8v w1f[4][2], w2f[4][2];
  #pragma unroll
  for (int nt = 0; nt < 4; nt++){
    int col = lr + 16*nt;
    #pragma unroll
    for (int ks = 0; ks < 2; ks++){
      const float* p1 = w1 + col*64 + ks*32 + lg*8;
      const float* p2 = w2 + col*64 + ks*32 + lg*8;
      short8v f, gg;
      #pragma unroll
      for (int j = 0; j < 8; j++){ f[j] = (short)f2b(p1[j]); gg[j] = (short)f2b(p2[j]); }
      w1f[nt][ks] = f; w2f[nt][ks] = gg;
    }
  }
  float b1l[4], b2l[4], gl[4], bl[4];
  #pragma unroll
  for (int nt = 0; nt < 4; nt++){
    int c = lr + 16*nt;
    b1l[nt] = b1[c]; b2l[nt] = b2[c]; gl[nt] = g[c]; bl[nt] = bb[c];
  }
  unsigned short* Tw = Tl[wid];
  unsigned short* Hw = Hl[wid];
  floatx4 zz = {0.f, 0.f, 0.f, 0.f};
  for (int tile = blockIdx.x; tile < NTILE; tile += gridDim.x){
    int row0 = tile*64 + wid*16;
    #pragma unroll
    for (int it = 0; it < 4; it++){
      int rl = it*4 + lg;
      size_t gi = (size_t)(row0 + rl)*64 + 4*lr;
      float4 x4 = ldf4(X1, gi);
      ushort4 tt;
      tt.x = f2b(x4.x); tt.y = f2b(x4.y); tt.z = f2b(x4.z); tt.w = f2b(x4.w);
      *(ushort4*)&Tw[swz(rl, 4*lr)] = tt;
    }
    wsync();
    short8v a0 = *(const short8v*)&Tw[swz(lr, lg*8)];
    short8v a1 = *(const short8v*)&Tw[swz(lr, 32 + lg*8)];
    #pragma unroll
    for (int nt = 0; nt < 4; nt++){
      floatx4 acc = zz;
      acc = __builtin_amdgcn_mfma_f32_16x16x32_bf16(a0, w1f[nt][0], acc, 0, 0, 0);
      acc = __builtin_amdgcn_mfma_f32_16x16x32_bf16(a1, w1f[nt][1], acc, 0, 0, 0);
      #pragma unroll
      for (int q = 0; q < 4; q++)
        Hw[swz(lg*4 + q, lr + 16*nt)] = f2b(fmaxf(acc[q] + b1l[nt], 0.f));
    }
    wsync();
    short8v h0 = *(const short8v*)&Hw[swz(lr, lg*8)];
    short8v h1 = *(const short8v*)&Hw[swz(lr, 32 + lg*8)];
    float y[4][4];
    float s[4] = {0.f,0.f,0.f,0.f}, ss[4] = {0.f,0.f,0.f,0.f};
    #pragma unroll
    for (int nt = 0; nt < 4; nt++){
      floatx4 acc = zz;
      acc = __builtin_amdgcn_mfma_f32_16x16x32_bf16(h0, w2f[nt][0], acc, 0, 0, 0);
      acc = __builtin_amdgcn_mfma_f32_16x16x32_bf16(h1, w2f[nt][1], acc, 0, 0, 0);
      #pragma unroll
      for (int q = 0; q < 4; q++){
        float xres = b2f(Tw[swz(lg*4 + q, lr + 16*nt)]);
        float v = acc[q] + b2l[nt] + xres;
        y[nt][q] = v; s[q] += v; ss[q] += v*v;
      }
    }
    #pragma unroll
    for (int o = 1; o < 16; o <<= 1){
      #pragma unroll
      for (int q = 0; q < 4; q++){
        s[q] += __shfl_xor(s[q], o, 64);
        ss[q] += __shfl_xor(ss[q], o, 64);
      }
    }
    float mu[4], rs[4];
    #pragma unroll
    for (int q = 0; q < 4; q++){
      mu[q] = s[q]*(1.f/64.f);
      float var = fmaxf(ss[q]*(1.f/64.f) - mu[q]*mu[q], 0.f);
      rs[q] = rsqrtf(var + LN_EPS);
    }
    #pragma unroll
    for (int nt = 0; nt < 4; nt++){
      #pragma unroll
      for (int q = 0; q < 4; q++){
        int rl = lg*4 + q, c = lr + 16*nt;
        out[(size_t)(row0 + rl)*64 + c] = (y[nt][q] - mu[q])*rs[q]*gl[nt] + bl[nt];
      }
    }
    wsync();
  }
}

// ---- init qk_x: out = mlp2(concat(x, noise)) ----
template<typename T>
__global__ __launch_bounds__(256) void initqk_mfma_kernel(
    const float* __restrict__ x, const float* __restrict__ noise,
    const float* __restrict__ w1, const float* __restrict__ b1,
    const float* __restrict__ w2, const float* __restrict__ b2,
    T* __restrict__ outp){
  __shared__ unsigned short Tl[4][1024];
  __shared__ unsigned short Hl[4][1024];
  __shared__ float Nl[4][16];
  int tid = threadIdx.x, lane = tid & 63, wid = tid >> 6;
  int lr = lane & 15, lg = lane >> 4;
  short8v w1f[4][2], w2f[4][2];
  float wnl[4];
  #pragma unroll
  for (int nt = 0; nt < 4; nt++){
    int col = lr + 16*nt;
    wnl[nt] = w1[col*65 + 64];
    #pragma unroll
    for (int ks = 0; ks < 2; ks++){
      const float* p1 = w1 + col*65 + ks*32 + lg*8;
      const float* p2 = w2 + col*64 + ks*32 + lg*8;
      short8v f, gg;
      #pragma unroll
      for (int j = 0; j < 8; j++){ f[j] = (short)f2b(p1[j]); gg[j] = (short)f2b(p2[j]); }
      w1f[nt][ks] = f; w2f[nt][ks] = gg;
    }
  }
  float b1l[4], b2l[4];
  #pragma unroll
  for (int nt = 0; nt < 4; nt++){
    int c = lr + 16*nt;
    b1l[nt] = b1[c]; b2l[nt] = b2[c];
  }
  unsigned short* Tw = Tl[wid];
  unsigned short* Hw = Hl[wid];
  floatx4 zz = {0.f, 0.f, 0.f, 0.f};
  for (int tile = blockIdx.x; tile < NTILE; tile += gridDim.x){
    int row0 = tile*64 + wid*16;
    #pragma unroll
    for (int it = 0; it < 4; it++){
      int rl = it*4 + lg;
      size_t gi = (size_t)(row0 + rl)*64 + 4*lr;
      float4 x4 = ldf4(x, gi);
      ushort4 tt;
      tt.x = f2b(x4.x); tt.y = f2b(x4.y); tt.z = f2b(x4.z); tt.w = f2b(x4.w);
      *(ushort4*)&Tw[swz(rl, 4*lr)] = tt;
      if (lr == 0) Nl[wid][rl] = noise[row0 + rl];
    }
    wsync();
    short8v a0 = *(const short8v*)&Tw[swz(lr, lg*8)];
    short8v a1 = *(const short8v*)&Tw[swz(lr, 32 + lg*8)];
    float nzq[4];
    #pragma unroll
    for (int q = 0; q < 4; q++) nzq[q] = Nl[wid][lg*4 + q];
    #pragma unroll
    for (int nt = 0; nt < 4; nt++){
      floatx4 acc = zz;
      acc = __builtin_amdgcn_mfma_f32_16x16x32_bf16(a0, w1f[nt][0], acc, 0, 0, 0);
      acc = __builtin_amdgcn_mfma_f32_16x16x32_bf16(a1, w1f[nt][1], acc, 0, 0, 0);
      #pragma unroll
      for (int q = 0; q < 4; q++)
        Hw[swz(lg*4 + q, lr + 16*nt)] = f2b(fmaxf(acc[q] + b1l[nt] + wnl[nt]*nzq[q], 0.f));
    }
    wsync();
    short8v h0 = *(const short8v*)&Hw[swz(lr, lg*8)];
    short8v h1 = *(const short8v*)&Hw[swz(lr, 32 + lg*8)];
    #pragma unroll
    for (int nt = 0; nt < 4; nt++){
      floatx4 acc = zz;
      acc = __builtin_amdgcn_mfma_f32_16x16x32_bf16(h0, w2f[nt][0], acc, 0, 0, 0);
      acc = __builtin_amdgcn_mfma_f32_16x16x32_bf16(h1, w2f[nt][1], acc, 0, 0, 0);
      #pragma unroll
      for (int q = 0; q < 4; q++){
        int rl = lg*4 + q, c = lr + 16*nt;
        stf(outp, (size_t)(row0 + rl)*64 + c, acc[q] + b2l[nt]);
      }
    }
    wsync();
  }
}

// ---- init v_x: out = mlp2(concat(x, onehot)) ----
template<typename T>
__global__ __launch_bounds__(256) void initv_mfma_kernel(
    const float* __restrict__ x, const int* __restrict__ h_index,
    const float* __restrict__ w1, const float* __restrict__ b1,
    const float* __restrict__ w2, const float* __restrict__ b2,
    T* __restrict__ outp){
  __shared__ unsigned short Tl[4][1024];
  __shared__ unsigned short Hl[4][1024];
  int tid = threadIdx.x, lane = tid & 63, wid = tid >> 6;
  int lr = lane & 15, lg = lane >> 4;
  short8v w1f[4][2], w2f[4][2];
  float rsvl[4];
  #pragma unroll
  for (int nt = 0; nt < 4; nt++){
    int col = lr + 16*nt;
    float rsv = 0.f;
    for (int d = 64; d < 128; d++) rsv += w1[col*128 + d];
    rsvl[nt] = rsv;
    #pragma unroll
    for (int ks = 0; ks < 2; ks++){
      const float* p1 = w1 + col*128 + ks*32 + lg*8;
      const float* p2 = w2 + col*64 + ks*32 + lg*8;
      short8v f, gg;
      #pragma unroll
      for (int j = 0; j < 8; j++){ f[j] = (short)f2b(p1[j]); gg[j] = (short)f2b(p2[j]); }
      w1f[nt][ks] = f; w2f[nt][ks] = gg;
    }
  }
  float b1l[4], b2l[4];
  #pragma unroll
  for (int nt = 0; nt < 4; nt++){
    int c = lr + 16*nt;
    b1l[nt] = b1[c]; b2l[nt] = b2[c];
  }
  int hi0 = h_index[0], hi1 = h_index[1], hi2 = h_index[2], hi3 = h_index[3];
  unsigned short* Tw = Tl[wid];
  unsigned short* Hw = Hl[wid];
  floatx4 zz = {0.f, 0.f, 0.f, 0.f};
  for (int tile = blockIdx.x; tile < NTILE; tile += gridDim.x){
    int row0 = tile*64 + wid*16;
    int b = row0 / VDIM;                       // wave-uniform (16 | 20000)
    int vb = row0 - b*VDIM;
    int hv = (b == 0) ? hi0 : (b == 1) ? hi1 : (b == 2) ? hi2 : hi3;
    #pragma unroll
    for (int it = 0; it < 4; it++){
      int rl = it*4 + lg;
      size_t gi = (size_t)(row0 + rl)*64 + 4*lr;
      float4 x4 = ldf4(x, gi);
      ushort4 tt;
      tt.x = f2b(x4.x); tt.y = f2b(x4.y); tt.z = f2b(x4.z); tt.w = f2b(x4.w);
      *(ushort4*)&Tw[swz(rl, 4*lr)] = tt;
    }
    wsync();
    short8v a0 = *(const short8v*)&Tw[swz(lr, lg*8)];
    short8v a1 = *(const short8v*)&Tw[swz(lr, 32 + lg*8)];
    bool cq[4];
    #pragma unroll
    for (int q = 0; q < 4; q++) cq[q] = (vb + lg*4 + q) == hv;
    #pragma unroll
    for (int nt = 0; nt < 4; nt++){
      floatx4 acc = zz;
      acc = __builtin_amdgcn_mfma_f32_16x16x32_bf16(a0, w1f[nt][0], acc, 0, 0, 0);
      acc = __builtin_amdgcn_mfma_f32_16x16x32_bf16(a1, w1f[nt][1], acc, 0, 0, 0);
      #pragma unroll
      for (int q = 0; q < 4; q++)
        Hw[swz(lg*4 + q, lr + 16*nt)] = f2b(fmaxf(acc[q] + b1l[nt] + (cq[q] ? rsvl[nt] : 0.f), 0.f));
    }
    wsync();
    short8v h0 = *(const short8v*)&Hw[swz(lr, lg*8)];
    short8v h1 = *(const short8v*)&Hw[swz(lr, 32 + lg*8)];
    #pragma unroll
    for (int nt = 0; nt < 4; nt++){
      floatx4 acc = zz;
      acc = __builtin_amdgcn_mfma_f32_16x16x32_bf16(h0, w2f[nt][0], acc, 0, 0, 0);
      acc = __builtin_amdgcn_mfma_f32_16x16x32_bf16(h1, w2f[nt][1], acc, 0, 0, 0);
      #pragma unroll
      for (int q = 0; q < 4; q++){
        int rl = lg*4 + q, c = lr + 16*nt;
        stf(outp, (size_t)(row0 + rl)*64 + c, acc[q] + b2l[nt]);
      }
    }
    wsync();
  }
}

// ---- kvred: k-projection + kv/ksum/vsum partials ----
template<typename T>
__global__ __launch_bounds__(256, 2) void kvred_kernel(
    const T* __restrict__ Xqk, const T* __restrict__ Xv,
    const float* __restrict__ w, const float* __restrict__ bias,
    float* __restrict__ partial){
  __shared__ __align__(16) float tb[16*64];
  __shared__ __align__(16) float red[4*1152];
  int tid = threadIdx.x, lane = tid & 63, wid = tid >> 6;
  float4 wk[16];
  const float4* wv = (const float4*)w;
  #pragma unroll
  for (int i = 0; i < 16; i++) wk[i] = wv[(64+lane)*16 + i];
  float bk = bias[64+lane];
  int b = blockIdx.x / NBB, blk = blockIdx.x % NBB;
  float kv[16];
  #pragma unroll
  for (int i = 0; i < 16; i++) kv[i] = 0.f;
  float ks = 0.f, vs = 0.f;
  const float4* tbv = (const float4*)tb;
  int tbase = wid*256 + lane;
  int fbase = wid*64;
  int base = lane & 48;                      // h*16
  const int STEPS = VDIM / (NBB*16);         // 5
  size_t row = ((size_t)b*VDIM + blk*16 + wid*4)*64 + lane;
  const size_t rstride = (size_t)NBB*16*64;
  float x0 = ldf(Xqk, row),     x1 = ldf(Xqk, row+64);
  float x2 = ldf(Xqk, row+128), x3 = ldf(Xqk, row+192);
  float u0 = ldf(Xv, row),      u1 = ldf(Xv, row+64);
  float u2 = ldf(Xv, row+128),  u3 = ldf(Xv, row+192);
  for (int st = 0; st < STEPS; st++){
    size_t nrow = row + rstride;
    size_t prow = (st + 1 < STEPS) ? nrow : row;
    float nx0 = ldf(Xqk, prow),     nx1 = ldf(Xqk, prow+64);
    float nx2 = ldf(Xqk, prow+128), nx3 = ldf(Xqk, prow+192);
    float nu0 = ldf(Xv, prow),      nu1 = ldf(Xv, prow+64);
    float nu2 = ldf(Xv, prow+128),  nu3 = ldf(Xv, prow+192);
    tb[tbase] = x0; tb[tbase+64] = x1; tb[tbase+128] = x2; tb[tbase+192] = x3;
    wsync();
    float k0=bk, k1=bk, k2=bk, k3=bk;
    #pragma unroll
    for (int i4 = 0; i4 < 16; i4++){
      float4 wkc = wk[i4];
      k0 += dot4(wkc, tbv[fbase + i4]);
      k1 += dot4(wkc, tbv[fbase + 16 + i4]);
      k2 += dot4(wkc, tbv[fbase + 32 + i4]);
      k3 += dot4(wkc, tbv[fbase + 48 + i4]);
    }
    float c0=k0*k0, c1=k1*k1, c2=k2*k2, c3=k3*k3;
    #pragma unroll
    for (int o = 8; o > 0; o >>= 1){
      c0 += __shfl_xor(c0,o,64); c1 += __shfl_xor(c1,o,64);
      c2 += __shfl_xor(c2,o,64); c3 += __shfl_xor(c3,o,64);
    }
    k0 /= fmaxf(sqrtf(c0), 1e-12f); k1 /= fmaxf(sqrtf(c1), 1e-12f);
    k2 /= fmaxf(sqrtf(c2), 1e-12f); k3 /= fmaxf(sqrtf(c3), 1e-12f);
    ks += k0 + k1 + k2 + k3;
    vs += u0 + u1 + u2 + u3;
    #pragma unroll
    for (int dl = 0; dl < 16; dl++){
      kv[dl] += k0*__shfl(u0, base+dl, 64)
              + k1*__shfl(u1, base+dl, 64)
              + k2*__shfl(u2, base+dl, 64)
              + k3*__shfl(u3, base+dl, 64);
    }
    row = nrow;
    x0=nx0; x1=nx1; x2=nx2; x3=nx3;
    u0=nu0; u1=nu1; u2=nu2; u3=nu3;
    wsync();
  }
  float* rw = red + wid*1152;
  #pragma unroll
  for (int dl = 0; dl < 16; dl++) rw[lane*16 + dl] = kv[dl];
  rw[1024 + lane] = ks;
  rw[1088 + lane] = vs;
  __syncthreads();
  float* P = partial + (size_t)blockIdx.x*1152;
  for (int j = tid; j < 1152; j += 256)
    P[j] = red[j] + red[1152+j] + red[2304+j] + red[3456+j];
}

// ---- reduce kvred partials ----
__global__ void qkred_kernel(const float* __restrict__ partial,
                             float* __restrict__ kvs, float* __restrict__ ksum, float* __restrict__ vsum){
  int b = blockIdx.x / 5, ch = blockIdx.x % 5;
  int j = ch*256 + threadIdx.x;
  if (j >= 1152) return;
  const float* P = partial + (size_t)b*NBB*1152;
  float s = 0.f;
  for (int t = 0; t < NBB; t++) s += P[(size_t)t*1152 + j];
  if (j < 1024)      kvs[b*1024 + j] = s;
  else if (j < 1088) ksum[b*64 + (j-1024)] = s;
  else               vsum[b*64 + (j-1088)] = s;
}

// ---- attention finalize: q-projection + head-norm + attention + LN ----
template<typename T>
__global__ __launch_bounds__(256, 2) void attn_final_kernel(
    const float* __restrict__ x, T* __restrict__ A, const T* __restrict__ Xv,
    const float* __restrict__ kvs, const float* __restrict__ ksum, const float* __restrict__ vsum,
    const float* __restrict__ w, const float* __restrict__ bias,
    const float* __restrict__ g, const float* __restrict__ bb){
  __shared__ float kvss[4096], kss[256], vss[256];
  __shared__ __align__(16) float tb[16*64];
  int tid = threadIdx.x, lane = tid & 63, wid = tid >> 6;
  float4 wq[16];
  const float4* wv = (const float4*)w;
  #pragma unroll
  for (int i = 0; i < 16; i++) wq[i] = wv[lane*16 + i];
  float bq = bias[lane];
  for (int i = tid; i < 4096; i += 256) kvss[i] = kvs[i];
  kss[tid] = ksum[tid];
  vss[tid] = vsum[tid];
  float gl = g[lane], bl = bb[lane];
  __syncthreads();
  int h16 = lane & 48, dl = lane & 15;
  const float4* tbv = (const float4*)tb;
  int tbase = wid*256 + lane;
  int fbase = wid*64;
  const size_t end = (size_t)BV*64;
  const size_t stride = (size_t)gridDim.x*16*64;
  size_t rb = ((size_t)blockIdx.x*16 + wid*4)*64 + lane;
  int rowi = blockIdx.x*16 + wid*4;
  float a0 = ldf(A, rb),      a1 = ldf(A, rb+64);
  float a2 = ldf(A, rb+128),  a3 = ldf(A, rb+192);
  float u0 = ldf(Xv, rb),     u1 = ldf(Xv, rb+64);
  float u2 = ldf(Xv, rb+128), u3 = ldf(Xv, rb+192);
  float xv0 = x[rb], xv1 = x[rb+64], xv2 = x[rb+128], xv3 = x[rb+192];
  for (; rb < end; rb += stride, rowi += gridDim.x*16){
    size_t nrb = rb + stride;
    size_t prow = (nrb < end) ? nrb : rb;
    float na0 = ldf(A, prow),      na1 = ldf(A, prow+64);
    float na2 = ldf(A, prow+128),  na3 = ldf(A, prow+192);
    float nu0 = ldf(Xv, prow),     nu1 = ldf(Xv, prow+64);
    float nu2 = ldf(Xv, prow+128), nu3 = ldf(Xv, prow+192);
    float nxv0 = x[prow], nxv1 = x[prow+64], nxv2 = x[prow+128], nxv3 = x[prow+192];
    int b = rowi / VDIM;                     // wave-uniform
    tb[tbase] = a0; tb[tbase+64] = a1; tb[tbase+128] = a2; tb[tbase+192] = a3;
    wsync();
    float q0=bq, q1=bq, q2=bq, q3=bq;
    #pragma unroll
    for (int i4 = 0; i4 < 16; i4++){
      float4 wqc = wq[i4];
      q0 += dot4(wqc, tbv[fbase + i4]);
      q1 += dot4(wqc, tbv[fbase + 16 + i4]);
      q2 += dot4(wqc, tbv[fbase + 32 + i4]);
      q3 += dot4(wqc, tbv[fbase + 48 + i4]);
    }
    float c0=q0*q0, c1=q1*q1, c2=q2*q2, c3=q3*q3;
    #pragma unroll
    for (int o = 8; o > 0; o >>= 1){
      c0 += __shfl_xor(c0,o,64); c1 += __shfl_xor(c1,o,64);
      c2 += __shfl_xor(c2,o,64); c3 += __shfl_xor(c3,o,64);
    }
    q0 /= fmaxf(sqrtf(c0), 1e-12f); q1 /= fmaxf(sqrtf(c1), 1e-12f);
    q2 /= fmaxf(sqrtf(c2), 1e-12f); q3 /= fmaxf(sqrtf(c3), 1e-12f);
    float vsb = vss[b*64+lane];
    float num0 = vsb + u0*(float)VDIM, num1 = vsb + u1*(float)VDIM;
    float num2 = vsb + u2*(float)VDIM, num3 = vsb + u3*(float)VDIM;
    float den0 = 2.0f*(float)VDIM, den1 = den0, den2 = den0, den3 = den0;
    int kbase = b*1024 + h16*16 + dl;
    int ksbase = b*64 + h16;
    #pragma unroll
    for (int j = 0; j < 16; j++){
      float kvj = kvss[kbase + j*16];
      float ksj = kss[ksbase + j];
      float qj0 = __shfl(q0, h16 + j, 64);
      float qj1 = __shfl(q1, h16 + j, 64);
      float qj2 = __shfl(q2, h16 + j, 64);
      float qj3 = __shfl(q3, h16 + j, 64);
      num0 += qj0*kvj; den0 += qj0*ksj;
      num1 += qj1*kvj; den1 += qj1*ksj;
      num2 += qj2*kvj; den2 += qj2*ksj;
      num3 += qj3*kvj; den3 += qj3*ksj;
    }
    float y0 = xv0 + num0/den0, y1 = xv1 + num1/den1;
    float y2 = xv2 + num2/den2, y3 = xv3 + num3/den3;
    float s0=y0, s1=y1, s2=y2, s3=y3;
    float t0=y0*y0, t1=y1*y1, t2=y2*y2, t3=y3*y3;
    #pragma unroll
    for (int o = 32; o > 0; o >>= 1){
      s0 += __shfl_xor(s0,o,64); t0 += __shfl_xor(t0,o,64);
      s1 += __shfl_xor(s1,o,64); t1 += __shfl_xor(t1,o,64);
      s2 += __shfl_xor(s2,o,64); t2 += __shfl_xor(t2,o,64);
      s3 += __shfl_xor(s3,o,64); t3 += __shfl_xor(t3,o,64);
    }
    float mu, var;
    mu = s0*(1.f/64.f); var = fmaxf(t0*(1.f/64.f) - mu*mu, 0.f);
    stf(A, rb,     (y0-mu)*rsqrtf(var+LN_EPS)*gl + bl);
    mu = s1*(1.f/64.f); var = fmaxf(t1*(1.f/64.f) - mu*mu, 0.f);
    stf(A, rb+64,  (y1-mu)*rsqrtf(var+LN_EPS)*gl + bl);
    mu = s2*(1.f/64.f); var = fmaxf(t2*(1.f/64.f) - mu*mu, 0.f);
    stf(A, rb+128, (y2-mu)*rsqrtf(var+LN_EPS)*gl + bl);
    mu = s3*(1.f/64.f); var = fmaxf(t3*(1.f/64.f) - mu*mu, 0.f);
    stf(A, rb+192, (y3-mu)*rsqrtf(var+LN_EPS)*gl + bl);
    a0=na0; a1=na1; a2=na2; a3=na3;
    u0=nu0; u1=nu1; u2=nu2; u3=nu3;
    xv0=nxv0; xv1=nxv1; xv2=nxv2; xv3=nxv3;
    wsync();
  }
}

// ================= host side =================
static const int DICT_SIZES[42] = {
  5120000,256,256,80000,262144,4096,4160,64,4096,64,
  8192,64,4096,64,8192,128,8192,128,8192,128,
  128,128,128,524288,8192,8192,128,8192,128,128,
  128,128,4096,64,4096,64,64,64,64,64,
  4,600000};

template<typename T>
static void run_pipeline(const float* const* N, const int* hi,
                         const int* row_ptr, const int2* pk,
                         float* qk_z, float* zr, float* kvs, float* part,
                         T* Obuf, T* A, T* B, float* outp, hipStream_t stream){
  float* ksum = kvs + 4096;
  float* vsum = kvs + 4352;

  zcalc_kernel<<<192, 256, 0, stream>>>(N[1], N[4], N[5], N[23], N[24], qk_z, zr);

  initqk_mfma_kernel<T><<<NTILE, 256, 0, stream>>>(N[0], N[3], N[6], N[7], N[8], N[9], A);
  for (int i = 0; i < 2; i++){
    rspmm_gather<T><<<VDIM/8, 256, 0, stream>>>(row_ptr, pk, qk_z, A, Obuf);
    loop_mfma_kernel<T><<<NTILE, 256, 0, stream>>>(Obuf, A, N[20] + i*64, N[16] + i*4096, N[17] + i*64,
                                                   N[18] + i*4096, N[19] + i*64, N[21] + i*64, N[22] + i*64);
  }
  initv_mfma_kernel<T><<<NTILE, 256, 0, stream>>>(N[0], hi, N[10], N[11], N[12], N[13], B);
  for (int i = 0; i < 2; i++){
    rspmm_gather<T><<<VDIM/8, 256, 0, stream>>>(row_ptr, pk, zr + i*16384, B, Obuf);
    loop_mfma_kernel<T><<<NTILE, 256, 0, stream>>>(Obuf, B, N[29] + i*64, N[25] + i*4096, N[26] + i*64,
                                                   N[27] + i*4096, N[28] + i*64, N[30] + i*64, N[31] + i*64);
  }
  kvred_kernel<T><<<BDIM*NBB, 256, 0, stream>>>(A, B, N[14], N[15], part);
  qkred_kernel<<<20, 256, 0, stream>>>(part, kvs, ksum, vsum);
  attn_final_kernel<T><<<GMD, 256, 0, stream>>>(N[0], A, B, kvs, ksum, vsum, N[14], N[15], N[36], N[37]);
  final_mfma_kernel<T><<<NTILE, 256, 0, stream>>>(A, N[32], N[33], N[34], N[35], N[38], N[39], outp);
}

extern "C" void kernel_launch(void* const* d_in, const int* in_sizes, int n_in,
                              void* d_out, int out_size, void* d_ws, size_t ws_size,
                              hipStream_t stream){
  float* outp = (float*)d_out;
  const int GOUT = (out_size + 255) / 256;

  if (n_in != 42){
    fill_kernel<<<GOUT, 256, 0, stream>>>(outp, 2000.0f + (float)n_in, out_size);
    return;
  }
  auto sz_ok = [&](int s, int e)->bool{
    if (s == e) return true;
    if ((e == 4 || e == 600000) && s == 2*e) return true;
    return false;
  };
  int bad = -1;
  for (int i = 0; i < 42 && bad < 0; i++)
    if (!sz_ok(in_sizes[i], DICT_SIZES[i])) bad = i;
  if (bad >= 0){
    fill_kernel<<<GOUT, 256, 0, stream>>>(outp, 1000.0f + (float)bad, out_size);
    return;
  }

  const float* N[40];
  for (int i = 0; i < 40; i++) N[i] = (const float*)d_in[i];
  const int* hi_raw = (const int*)d_in[40];
  const int* ei_raw = (const int*)d_in[41];

  char* p = (char*)d_ws;
  auto alloc = [&](size_t bytes)->char*{ char* r = p; p += (bytes + 255) / 256 * 256; return r; };
  int* ei      = (int*)alloc((size_t)3*EDIM*4);
  int* hi      = (int*)alloc(256);
  int* eflag   = (int*)alloc(256);
  int* counts  = (int*)alloc((VDIM+1)*4);
  int* row_ptr = (int*)alloc((VDIM+1)*4);
  int* cursor  = (int*)alloc((VDIM+1)*4);
  int2* pk     = (int2*)alloc((size_t)EDIM*8);
  float* qk_z  = (float*)alloc(16384u*4);
  float* zr    = (float*)alloc(32768u*4);
  float* kvs   = (float*)alloc(4608u*4);
  float* part  = (float*)alloc((size_t)BDIM*NBB*1152*4);
  size_t fixed = (size_t)(p - (char*)d_ws);
  bool f32ok = ws_size >= fixed + 3*(size_t)BV*64*4 + 1024;

  detect_kernel<<<1, 256, 0, stream>>>(ei_raw, eflag);
  prep_idx_kernel<<<(3*EDIM+255)/256, 256, 0, stream>>>(ei_raw, hi_raw, eflag, ei, hi);
  zero_kernel<<<(VDIM+256)/256, 256, 0, stream>>>(counts);
  count_kernel<<<(EDIM+255)/256, 256, 0, stream>>>(ei, counts);
  scan_kernel<<<1, 256, 0, stream>>>(counts, row_ptr, cursor);
  scatter_kernel<<<(EDIM+255)/256, 256, 0, stream>>>(ei, cursor, pk);

  if (f32ok){
    float* Obuf = (float*)alloc((size_t)BV*64*4);
    float* A    = (float*)alloc((size_t)BV*64*4);
    float* B    = (float*)alloc((size_t)BV*64*4);
    run_pipeline<float>(N, hi, row_ptr, pk, qk_z, zr, kvs, part, Obuf, A, B, outp, stream);
  } else {
    bf16* Obuf = (bf16*)alloc((size_t)BV*64*2);
    bf16* A    = (bf16*)alloc((size_t)BV*64*2);
    bf16* B    = (bf16*)alloc((size_t)BV*64*2);
    run_pipeline<bf16>(N, hi, row_ptr, pk, qk_z, zr, kvs, part, Obuf, A, B, outp, stream);
  }
}

// Round 5
// 679.496 us; speedup vs baseline: 1.4432x; 1.1056x over previous
//
#include <hip/hip_runtime.h>
#include <hip/hip_bf16.h>

#define BDIM 4
#define VDIM 20000
#define DDIM 64
#define RDIM 64
#define EDIM 200000
#define BV (BDIM*VDIM)
#define LN_EPS 1e-5f
#define NBB 125           // kvred blocks per batch
#define NTILE 1250        // BV/64 row-tiles for MFMA kernels

typedef __hip_bfloat16 bf16;
typedef __attribute__((ext_vector_type(8))) short short8v;
typedef __attribute__((ext_vector_type(4))) float floatx4;

__device__ __forceinline__ float ldf(const float* p, size_t i){ return p[i]; }
__device__ __forceinline__ float ldf(const bf16* p, size_t i){ return __bfloat162float(p[i]); }
__device__ __forceinline__ void stf(float* p, size_t i, float v){ p[i] = v; }
__device__ __forceinline__ void stf(bf16* p, size_t i, float v){ p[i] = __float2bfloat16(v); }

__device__ __forceinline__ unsigned short f2b(float f){
  unsigned u = __builtin_bit_cast(unsigned, f);
  u += 0x7fffu + ((u >> 16) & 1u);
  return (unsigned short)(u >> 16);
}
__device__ __forceinline__ float b2f(unsigned short h){
  unsigned u = ((unsigned)h) << 16;
  return __builtin_bit_cast(float, u);
}
__device__ __forceinline__ float4 ldf4(const float* p, size_t i){ return *(const float4*)(p+i); }
__device__ __forceinline__ float4 ldf4(const bf16* p, size_t i){
  ushort4 u = *(const ushort4*)(p+i);
  return make_float4(b2f(u.x), b2f(u.y), b2f(u.z), b2f(u.w));
}
// LDS tile swizzle: element index for [16][64] bf16 tile, 16B-unit XOR on row
__device__ __forceinline__ int swz(int r, int c){ return r*64 + (c ^ ((r & 7) << 3)); }

__device__ __forceinline__ float dot4(float4 a, float4 b){
  return a.x*b.x + a.y*b.y + a.z*b.z + a.w*b.w;
}

// Wave-private LDS ordering: DS ops from one wave execute in order; just fence compiler.
__device__ __forceinline__ void wsync(){
  __builtin_amdgcn_wave_barrier();
  __asm__ volatile("" ::: "memory");
}

// ---- diagnostic fill ----
__global__ void fill_kernel(float* __restrict__ out, float v, int n){
  int t = blockIdx.x * 256 + threadIdx.x;
  if (t < n) out[t] = v;
}

// ---- detect 64-bit index layout once ----
__global__ void detect_kernel(const int* __restrict__ ei_raw, int* __restrict__ flag){
  int tid = threadIdx.x;
  int nz = 0;
  for (int j = 2*tid + 1; j < 1024; j += 512) nz |= (ei_raw[j] != 0);
  nz = __any(nz);
  __shared__ int r[4];
  if ((tid & 63) == 0) r[tid >> 6] = nz;
  __syncthreads();
  if (tid == 0) flag[0] = (r[0] | r[1] | r[2] | r[3]) ? 0 : 1;   // 1 => 64-bit
}

__global__ void prep_idx_kernel(const int* __restrict__ ei_raw, const int* __restrict__ hi_raw,
                                const int* __restrict__ flag,
                                int* __restrict__ ei, int* __restrict__ hi){
  int is64 = flag[0];
  int t = blockIdx.x * 256 + threadIdx.x;
  if (t < 3*EDIM) ei[t] = is64 ? ei_raw[2*t] : ei_raw[t];
  if (t < BDIM)   hi[t] = is64 ? hi_raw[2*t] : hi_raw[t];
}

__global__ void zero_kernel(int* __restrict__ counts){
  int i = blockIdx.x * 256 + threadIdx.x;
  if (i < VDIM + 1) counts[i] = 0;
}

__global__ void count_kernel(const int* __restrict__ ei, int* __restrict__ counts){
  int e = blockIdx.x * 256 + threadIdx.x;
  if (e < EDIM){
    int dst = ei[e*3], rel = ei[e*3+1], src = ei[e*3+2];
    if ((unsigned)dst < VDIM && (unsigned)rel < RDIM && (unsigned)src < VDIM)
      atomicAdd(&counts[dst], 1);
  }
}

// ---- scan: per-thread segments + one wave scan, 1 barrier total ----
__global__ void scan_kernel(const int* __restrict__ counts, int* __restrict__ row_ptr, int* __restrict__ cursor){
  __shared__ int wsum[4];
  int tid = threadIdx.x, lane = tid & 63, wid = tid >> 6;
  const int SEG = (VDIM + 255) / 256;        // 79
  int lo = tid * SEG;
  int hi = lo + SEG; if (hi > VDIM) hi = VDIM;
  int s = 0;
  for (int i = lo; i < hi; i++) s += counts[i];
  int x = s;
  #pragma unroll
  for (int o = 1; o < 64; o <<= 1){
    int t = __shfl_up(x, o, 64);
    if (lane >= o) x += t;
  }
  if (lane == 63) wsum[wid] = x;
  __syncthreads();
  int wo = 0;
  for (int w = 0; w < wid; w++) wo += wsum[w];
  int run = wo + x - s;                      // exclusive prefix of this thread's segment
  for (int i = lo; i < hi; i++){
    row_ptr[i] = run; cursor[i] = run; run += counts[i];
  }
  if (tid == 255) row_ptr[VDIM] = run;       // total
}

__global__ void scatter_kernel(const int* __restrict__ ei, int* __restrict__ cursor,
                               int2* __restrict__ pk){
  int e = blockIdx.x * 256 + threadIdx.x;
  if (e < EDIM){
    int dst = ei[e*3], rel = ei[e*3+1], src = ei[e*3+2];
    if ((unsigned)dst < VDIM && (unsigned)rel < RDIM && (unsigned)src < VDIM){
      int p = atomicAdd(&cursor[dst], 1);
      pk[p] = make_int2(rel, src);
    }
  }
}

// ---- z projections (float4 weight reads) ----
__global__ void zcalc_kernel(const float* __restrict__ z,
                             const float* __restrict__ qkzw, const float* __restrict__ qkzb,
                             const float* __restrict__ vfw,  const float* __restrict__ vfb,
                             float* __restrict__ qk_z, float* __restrict__ zr){
  int idx = blockIdx.x * 256 + threadIdx.x;
  if (idx >= 49152) return;
  int which = idx >> 14;
  int r = idx & 16383;
  int b = r >> 12;
  int j = r & 4095;
  const float* wrow; float bias; float* outp;
  if (which == 0){ wrow = qkzw + (size_t)j*DDIM; bias = qkzb[j]; outp = qk_z; }
  else { int i = which - 1; wrow = vfw + (size_t)(i*4096 + j)*DDIM; bias = vfb[i*4096 + j]; outp = zr + i*16384; }
  const float4* zr4 = (const float4*)(z + (size_t)b*DDIM);
  const float4* wr4 = (const float4*)wrow;
  float acc = bias;
  #pragma unroll
  for (int i = 0; i < 16; i++) acc += dot4(zr4[i], wr4[i]);
  outp[r] = acc;
}

// ---- rspmm gather (CSR, packed idx), 8 vertices/block, 2 edges in flight ----
template<typename T>
__global__ __launch_bounds__(256) void rspmm_gather(
    const int* __restrict__ row_ptr, const int2* __restrict__ pk,
    const float* __restrict__ zrel, const T* __restrict__ X, T* __restrict__ out){
  int v0 = blockIdx.x * 8;
  int btch = threadIdx.x >> 6, d = threadIdx.x & 63;
  int rp[9];
  #pragma unroll
  for (int i = 0; i < 9; i++) rp[i] = row_ptr[v0 + i];
  const float* zb = zrel + btch*RDIM*DDIM + d;
  size_t xb = (size_t)btch*VDIM*64 + d;
  size_t ob = ((size_t)btch*VDIM + v0)*64 + d;
  #pragma unroll 1
  for (int vi = 0; vi < 8; vi++){
    int s = rp[vi], e = rp[vi+1];
    float acc0 = 0.f, acc1 = 0.f;
    int i = s;
    for (; i + 2 <= e; i += 2){
      int2 e0 = pk[i], e1 = pk[i+1];
      float x0 = ldf(X, xb + (size_t)e0.y*64);
      float x1 = ldf(X, xb + (size_t)e1.y*64);
      acc0 += zb[(size_t)e0.x*64] * x0;
      acc1 += zb[(size_t)e1.x*64] * x1;
    }
    if (i < e){
      int2 ed = pk[i];
      acc0 += zb[(size_t)ed.x*64] * ldf(X, xb + (size_t)ed.y*64);
    }
    stf(out, ob + (size_t)vi*64, acc0 + acc1);
  }
}

// ================= MFMA dense kernels =================
// Per wave: 16-row x 64-col tile. A-frag: lane holds row (lane&15), k-slice (lane>>4).
// B-frag (weights): lane holds W[col=(lane&15)+16nt][k-slice]. C/D: col=lane&15,
// row=(lane>>4)*4+q (m89-verified). LDS tiles [16][64] bf16 with row-XOR swizzle.

// ---- loop body: X = LN(mlp2(O + alpha*X))*ng + nb + X ----
template<typename T>
__global__ __launch_bounds__(256) void loop_mfma_kernel(
    const T* __restrict__ O, T* __restrict__ X,
    const float* __restrict__ alpha, const float* __restrict__ w1, const float* __restrict__ b1,
    const float* __restrict__ w2, const float* __restrict__ b2,
    const float* __restrict__ ng, const float* __restrict__ nb){
  __shared__ unsigned short Tl[4][1024];
  __shared__ unsigned short Xl[4][1024];
  __shared__ unsigned short Hl[4][1024];
  int tid = threadIdx.x, lane = tid & 63, wid = tid >> 6;
  int lr = lane & 15, lg = lane >> 4;
  short8v w1f[4][2], w2f[4][2];
  #pragma unroll
  for (int nt = 0; nt < 4; nt++){
    int col = lr + 16*nt;
    #pragma unroll
    for (int ks = 0; ks < 2; ks++){
      const float* p1 = w1 + col*64 + ks*32 + lg*8;
      const float* p2 = w2 + col*64 + ks*32 + lg*8;
      short8v f, g;
      #pragma unroll
      for (int j = 0; j < 8; j++){ f[j] = (short)f2b(p1[j]); g[j] = (short)f2b(p2[j]); }
      w1f[nt][ks] = f; w2f[nt][ks] = g;
    }
  }
  float4 al = ((const float4*)alpha)[lr];
  float b1l[4], b2l[4], ngl[4], nbl[4];
  #pragma unroll
  for (int nt = 0; nt < 4; nt++){
    int c = lr + 16*nt;
    b1l[nt] = b1[c]; b2l[nt] = b2[c]; ngl[nt] = ng[c]; nbl[nt] = nb[c];
  }
  unsigned short* Tw = Tl[wid];
  unsigned short* Xw = Xl[wid];
  unsigned short* Hw = Hl[wid];
  floatx4 zz = {0.f, 0.f, 0.f, 0.f};
  for (int tile = blockIdx.x; tile < NTILE; tile += gridDim.x){
    int row0 = tile*64 + wid*16;
    #pragma unroll
    for (int it = 0; it < 4; it++){
      int rl = it*4 + lg;
      size_t gi = (size_t)(row0 + rl)*64 + 4*lr;
      float4 xs4 = ldf4(X, gi);
      float4 ov4 = ldf4(O, gi);
      int si = swz(rl, 4*lr);
      ushort4 tt;
      tt.x = f2b(ov4.x + al.x*xs4.x);
      tt.y = f2b(ov4.y + al.y*xs4.y);
      tt.z = f2b(ov4.z + al.z*xs4.z);
      tt.w = f2b(ov4.w + al.w*xs4.w);
      *(ushort4*)&Tw[si] = tt;
      ushort4 xx;
      xx.x = f2b(xs4.x); xx.y = f2b(xs4.y); xx.z = f2b(xs4.z); xx.w = f2b(xs4.w);
      *(ushort4*)&Xw[si] = xx;
    }
    wsync();
    short8v a0 = *(const short8v*)&Tw[swz(lr, lg*8)];
    short8v a1 = *(const short8v*)&Tw[swz(lr, 32 + lg*8)];
    #pragma unroll
    for (int nt = 0; nt < 4; nt++){
      floatx4 acc = zz;
      acc = __builtin_amdgcn_mfma_f32_16x16x32_bf16(a0, w1f[nt][0], acc, 0, 0, 0);
      acc = __builtin_amdgcn_mfma_f32_16x16x32_bf16(a1, w1f[nt][1], acc, 0, 0, 0);
      #pragma unroll
      for (int q = 0; q < 4; q++)
        Hw[swz(lg*4 + q, lr + 16*nt)] = f2b(fmaxf(acc[q] + b1l[nt], 0.f));
    }
    wsync();
    short8v h0 = *(const short8v*)&Hw[swz(lr, lg*8)];
    short8v h1 = *(const short8v*)&Hw[swz(lr, 32 + lg*8)];
    float y[4][4];
    float s[4] = {0.f,0.f,0.f,0.f}, ss[4] = {0.f,0.f,0.f,0.f};
    #pragma unroll
    for (int nt = 0; nt < 4; nt++){
      floatx4 acc = zz;
      acc = __builtin_amdgcn_mfma_f32_16x16x32_bf16(h0, w2f[nt][0], acc, 0, 0, 0);
      acc = __builtin_amdgcn_mfma_f32_16x16x32_bf16(h1, w2f[nt][1], acc, 0, 0, 0);
      #pragma unroll
      for (int q = 0; q < 4; q++){
        float v = acc[q] + b2l[nt];
        y[nt][q] = v; s[q] += v; ss[q] += v*v;
      }
    }
    #pragma unroll
    for (int o = 1; o < 16; o <<= 1){
      #pragma unroll
      for (int q = 0; q < 4; q++){
        s[q] += __shfl_xor(s[q], o, 64);
        ss[q] += __shfl_xor(ss[q], o, 64);
      }
    }
    float mu[4], rs[4];
    #pragma unroll
    for (int q = 0; q < 4; q++){
      mu[q] = s[q]*(1.f/64.f);
      float var = fmaxf(ss[q]*(1.f/64.f) - mu[q]*mu[q], 0.f);
      rs[q] = rsqrtf(var + LN_EPS);
    }
    #pragma unroll
    for (int nt = 0; nt < 4; nt++){
      #pragma unroll
      for (int q = 0; q < 4; q++){
        int rl = lg*4 + q, c = lr + 16*nt;
        float xs = b2f(Xw[swz(rl, c)]);
        float v = (y[nt][q] - mu[q])*rs[q]*ngl[nt] + nbl[nt] + xs;
        stf(X, (size_t)(row0 + rl)*64 + c, v);
      }
    }
    wsync();
  }
}

// ---- final: out = LN(X1 + mlp2(X1))*g + b  (fp32 out) ----
template<typename T>
__global__ __launch_bounds__(256) void final_mfma_kernel(
    const T* __restrict__ X1,
    const float* __restrict__ w1, const float* __restrict__ b1,
    const float* __restrict__ w2, const float* __restrict__ b2,
    const float* __restrict__ g, const float* __restrict__ bb,
    float* __restrict__ out){
  __shared__ unsigned short Tl[4][1024];
  __shared__ unsigned short Hl[4][1024];
  int tid = threadIdx.x, lane = tid & 63, wid = tid >> 6;
  int lr = lane & 15, lg = lane >> 4;
  short8v w1f[4][2], w2f[4][2];
  #pragma unroll
  for (int nt = 0; nt < 4; nt++){
    int col = lr + 16*nt;
    #pragma unroll
    for (int ks = 0; ks < 2; ks++){
      const float* p1 = w1 + col*64 + ks*32 + lg*8;
      const float* p2 = w2 + col*64 + ks*32 + lg*8;
      short8v f, gg;
      #pragma unroll
      for (int j = 0; j < 8; j++){ f[j] = (short)f2b(p1[j]); gg[j] = (short)f2b(p2[j]); }
      w1f[nt][ks] = f; w2f[nt][ks] = gg;
    }
  }
  float b1l[4], b2l[4], gl[4], bl[4];
  #pragma unroll
  for (int nt = 0; nt < 4; nt++){
    int c = lr + 16*nt;
    b1l[nt] = b1[c]; b2l[nt] = b2[c]; gl[nt] = g[c]; bl[nt] = bb[c];
  }
  unsigned short* Tw = Tl[wid];
  unsigned short* Hw = Hl[wid];
  floatx4 zz = {0.f, 0.f, 0.f, 0.f};
  for (int tile = blockIdx.x; tile < NTILE; tile += gridDim.x){
    int row0 = tile*64 + wid*16;
    #pragma unroll
    for (int it = 0; it < 4; it++){
      int rl = it*4 + lg;
      size_t gi = (size_t)(row0 + rl)*64 + 4*lr;
      float4 x4 = ldf4(X1, gi);
      ushort4 tt;
      tt.x = f2b(x4.x); tt.y = f2b(x4.y); tt.z = f2b(x4.z); tt.w = f2b(x4.w);
      *(ushort4*)&Tw[swz(rl, 4*lr)] = tt;
    }
    wsync();
    short8v a0 = *(const short8v*)&Tw[swz(lr, lg*8)];
    short8v a1 = *(const short8v*)&Tw[swz(lr, 32 + lg*8)];
    #pragma unroll
    for (int nt = 0; nt < 4; nt++){
      floatx4 acc = zz;
      acc = __builtin_amdgcn_mfma_f32_16x16x32_bf16(a0, w1f[nt][0], acc, 0, 0, 0);
      acc = __builtin_amdgcn_mfma_f32_16x16x32_bf16(a1, w1f[nt][1], acc, 0, 0, 0);
      #pragma unroll
      for (int q = 0; q < 4; q++)
        Hw[swz(lg*4 + q, lr + 16*nt)] = f2b(fmaxf(acc[q] + b1l[nt], 0.f));
    }
    wsync();
    short8v h0 = *(const short8v*)&Hw[swz(lr, lg*8)];
    short8v h1 = *(const short8v*)&Hw[swz(lr, 32 + lg*8)];
    float y[4][4];
    float s[4] = {0.f,0.f,0.f,0.f}, ss[4] = {0.f,0.f,0.f,0.f};
    #pragma unroll
    for (int nt = 0; nt < 4; nt++){
      floatx4 acc = zz;
      acc = __builtin_amdgcn_mfma_f32_16x16x32_bf16(h0, w2f[nt][0], acc, 0, 0, 0);
      acc = __builtin_amdgcn_mfma_f32_16x16x32_bf16(h1, w2f[nt][1], acc, 0, 0, 0);
      #pragma unroll
      for (int q = 0; q < 4; q++){
        float xres = b2f(Tw[swz(lg*4 + q, lr + 16*nt)]);
        float v = acc[q] + b2l[nt] + xres;
        y[nt][q] = v; s[q] += v; ss[q] += v*v;
      }
    }
    #pragma unroll
    for (int o = 1; o < 16; o <<= 1){
      #pragma unroll
      for (int q = 0; q < 4; q++){
        s[q] += __shfl_xor(s[q], o, 64);
        ss[q] += __shfl_xor(ss[q], o, 64);
      }
    }
    float mu[4], rs[4];
    #pragma unroll
    for (int q = 0; q < 4; q++){
      mu[q] = s[q]*(1.f/64.f);
      float var = fmaxf(ss[q]*(1.f/64.f) - mu[q]*mu[q], 0.f);
      rs[q] = rsqrtf(var + LN_EPS);
    }
    #pragma unroll
    for (int nt = 0; nt < 4; nt++){
      #pragma unroll
      for (int q = 0; q < 4; q++){
        int rl = lg*4 + q, c = lr + 16*nt;
        out[(size_t)(row0 + rl)*64 + c] = (y[nt][q] - mu[q])*rs[q]*gl[nt] + bl[nt];
      }
    }
    wsync();
  }
}

// ---- init qk_x: out = mlp2(concat(x, noise)) ----
template<typename T>
__global__ __launch_bounds__(256) void initqk_mfma_kernel(
    const float* __restrict__ x, const float* __restrict__ noise,
    const float* __restrict__ w1, const float* __restrict__ b1,
    const float* __restrict__ w2, const float* __restrict__ b2,
    T* __restrict__ outp){
  __shared__ unsigned short Tl[4][1024];
  __shared__ unsigned short Hl[4][1024];
  __shared__ float Nl[4][16];
  int tid = threadIdx.x, lane = tid & 63, wid = tid >> 6;
  int lr = lane & 15, lg = lane >> 4;
  short8v w1f[4][2], w2f[4][2];
  float wnl[4];
  #pragma unroll
  for (int nt = 0; nt < 4; nt++){
    int col = lr + 16*nt;
    wnl[nt] = w1[col*65 + 64];
    #pragma unroll
    for (int ks = 0; ks < 2; ks++){
      const float* p1 = w1 + col*65 + ks*32 + lg*8;
      const float* p2 = w2 + col*64 + ks*32 + lg*8;
      short8v f, gg;
      #pragma unroll
      for (int j = 0; j < 8; j++){ f[j] = (short)f2b(p1[j]); gg[j] = (short)f2b(p2[j]); }
      w1f[nt][ks] = f; w2f[nt][ks] = gg;
    }
  }
  float b1l[4], b2l[4];
  #pragma unroll
  for (int nt = 0; nt < 4; nt++){
    int c = lr + 16*nt;
    b1l[nt] = b1[c]; b2l[nt] = b2[c];
  }
  unsigned short* Tw = Tl[wid];
  unsigned short* Hw = Hl[wid];
  floatx4 zz = {0.f, 0.f, 0.f, 0.f};
  for (int tile = blockIdx.x; tile < NTILE; tile += gridDim.x){
    int row0 = tile*64 + wid*16;
    #pragma unroll
    for (int it = 0; it < 4; it++){
      int rl = it*4 + lg;
      size_t gi = (size_t)(row0 + rl)*64 + 4*lr;
      float4 x4 = ldf4(x, gi);
      ushort4 tt;
      tt.x = f2b(x4.x); tt.y = f2b(x4.y); tt.z = f2b(x4.z); tt.w = f2b(x4.w);
      *(ushort4*)&Tw[swz(rl, 4*lr)] = tt;
      if (lr == 0) Nl[wid][rl] = noise[row0 + rl];
    }
    wsync();
    short8v a0 = *(const short8v*)&Tw[swz(lr, lg*8)];
    short8v a1 = *(const short8v*)&Tw[swz(lr, 32 + lg*8)];
    float nzq[4];
    #pragma unroll
    for (int q = 0; q < 4; q++) nzq[q] = Nl[wid][lg*4 + q];
    #pragma unroll
    for (int nt = 0; nt < 4; nt++){
      floatx4 acc = zz;
      acc = __builtin_amdgcn_mfma_f32_16x16x32_bf16(a0, w1f[nt][0], acc, 0, 0, 0);
      acc = __builtin_amdgcn_mfma_f32_16x16x32_bf16(a1, w1f[nt][1], acc, 0, 0, 0);
      #pragma unroll
      for (int q = 0; q < 4; q++)
        Hw[swz(lg*4 + q, lr + 16*nt)] = f2b(fmaxf(acc[q] + b1l[nt] + wnl[nt]*nzq[q], 0.f));
    }
    wsync();
    short8v h0 = *(const short8v*)&Hw[swz(lr, lg*8)];
    short8v h1 = *(const short8v*)&Hw[swz(lr, 32 + lg*8)];
    #pragma unroll
    for (int nt = 0; nt < 4; nt++){
      floatx4 acc = zz;
      acc = __builtin_amdgcn_mfma_f32_16x16x32_bf16(h0, w2f[nt][0], acc, 0, 0, 0);
      acc = __builtin_amdgcn_mfma_f32_16x16x32_bf16(h1, w2f[nt][1], acc, 0, 0, 0);
      #pragma unroll
      for (int q = 0; q < 4; q++){
        int rl = lg*4 + q, c = lr + 16*nt;
        stf(outp, (size_t)(row0 + rl)*64 + c, acc[q] + b2l[nt]);
      }
    }
    wsync();
  }
}

// ---- init v_x: out = mlp2(concat(x, onehot)) ----
template<typename T>
__global__ __launch_bounds__(256) void initv_mfma_kernel(
    const float* __restrict__ x, const int* __restrict__ h_index,
    const float* __restrict__ w1, const float* __restrict__ b1,
    const float* __restrict__ w2, const float* __restrict__ b2,
    T* __restrict__ outp){
  __shared__ unsigned short Tl[4][1024];
  __shared__ unsigned short Hl[4][1024];
  int tid = threadIdx.x, lane = tid & 63, wid = tid >> 6;
  int lr = lane & 15, lg = lane >> 4;
  short8v w1f[4][2], w2f[4][2];
  float rsvl[4];
  #pragma unroll
  for (int nt = 0; nt < 4; nt++){
    int col = lr + 16*nt;
    float rsv = 0.f;
    for (int d = 64; d < 128; d++) rsv += w1[col*128 + d];
    rsvl[nt] = rsv;
    #pragma unroll
    for (int ks = 0; ks < 2; ks++){
      const float* p1 = w1 + col*128 + ks*32 + lg*8;
      const float* p2 = w2 + col*64 + ks*32 + lg*8;
      short8v f, gg;
      #pragma unroll
      for (int j = 0; j < 8; j++){ f[j] = (short)f2b(p1[j]); gg[j] = (short)f2b(p2[j]); }
      w1f[nt][ks] = f; w2f[nt][ks] = gg;
    }
  }
  float b1l[4], b2l[4];
  #pragma unroll
  for (int nt = 0; nt < 4; nt++){
    int c = lr + 16*nt;
    b1l[nt] = b1[c]; b2l[nt] = b2[c];
  }
  int hi0 = h_index[0], hi1 = h_index[1], hi2 = h_index[2], hi3 = h_index[3];
  unsigned short* Tw = Tl[wid];
  unsigned short* Hw = Hl[wid];
  floatx4 zz = {0.f, 0.f, 0.f, 0.f};
  for (int tile = blockIdx.x; tile < NTILE; tile += gridDim.x){
    int row0 = tile*64 + wid*16;
    int b = row0 / VDIM;                       // wave-uniform (16 | 20000)
    int vb = row0 - b*VDIM;
    int hv = (b == 0) ? hi0 : (b == 1) ? hi1 : (b == 2) ? hi2 : hi3;
    #pragma unroll
    for (int it = 0; it < 4; it++){
      int rl = it*4 + lg;
      size_t gi = (size_t)(row0 + rl)*64 + 4*lr;
      float4 x4 = ldf4(x, gi);
      ushort4 tt;
      tt.x = f2b(x4.x); tt.y = f2b(x4.y); tt.z = f2b(x4.z); tt.w = f2b(x4.w);
      *(ushort4*)&Tw[swz(rl, 4*lr)] = tt;
    }
    wsync();
    short8v a0 = *(const short8v*)&Tw[swz(lr, lg*8)];
    short8v a1 = *(const short8v*)&Tw[swz(lr, 32 + lg*8)];
    bool cq[4];
    #pragma unroll
    for (int q = 0; q < 4; q++) cq[q] = (vb + lg*4 + q) == hv;
    #pragma unroll
    for (int nt = 0; nt < 4; nt++){
      floatx4 acc = zz;
      acc = __builtin_amdgcn_mfma_f32_16x16x32_bf16(a0, w1f[nt][0], acc, 0, 0, 0);
      acc = __builtin_amdgcn_mfma_f32_16x16x32_bf16(a1, w1f[nt][1], acc, 0, 0, 0);
      #pragma unroll
      for (int q = 0; q < 4; q++)
        Hw[swz(lg*4 + q, lr + 16*nt)] = f2b(fmaxf(acc[q] + b1l[nt] + (cq[q] ? rsvl[nt] : 0.f), 0.f));
    }
    wsync();
    short8v h0 = *(const short8v*)&Hw[swz(lr, lg*8)];
    short8v h1 = *(const short8v*)&Hw[swz(lr, 32 + lg*8)];
    #pragma unroll
    for (int nt = 0; nt < 4; nt++){
      floatx4 acc = zz;
      acc = __builtin_amdgcn_mfma_f32_16x16x32_bf16(h0, w2f[nt][0], acc, 0, 0, 0);
      acc = __builtin_amdgcn_mfma_f32_16x16x32_bf16(h1, w2f[nt][1], acc, 0, 0, 0);
      #pragma unroll
      for (int q = 0; q < 4; q++){
        int rl = lg*4 + q, c = lr + 16*nt;
        stf(outp, (size_t)(row0 + rl)*64 + c, acc[q] + b2l[nt]);
      }
    }
    wsync();
  }
}

// ---- kvred (MFMA): k-proj + head-norm + kv += kn^T·vx + ksum/vsum partials ----
template<typename T>
__global__ __launch_bounds__(256) void kvred_mfma_kernel(
    const T* __restrict__ Xqk, const T* __restrict__ Xv,
    const float* __restrict__ w, const float* __restrict__ bias,
    float* __restrict__ partial){
  __shared__ unsigned short T1[4][1024];   // Xqk stage (swz) then kn_t [64][16]
  __shared__ unsigned short T2[4][1024];   // Xv stage (swz)
  __shared__ float red[4*1536];
  int tid = threadIdx.x, lane = tid & 63, wid = tid >> 6;
  int lr = lane & 15, lg = lane >> 4;
  short8v wkf[4][2];
  #pragma unroll
  for (int nt = 0; nt < 4; nt++){
    int col = 64 + lr + 16*nt;               // k-half of fc_to_qk
    #pragma unroll
    for (int ks = 0; ks < 2; ks++){
      const float* p = w + col*64 + ks*32 + lg*8;
      short8v f;
      #pragma unroll
      for (int j = 0; j < 8; j++) f[j] = (short)f2b(p[j]);
      wkf[nt][ks] = f;
    }
  }
  float bk[4];
  #pragma unroll
  for (int nt = 0; nt < 4; nt++) bk[nt] = bias[64 + lr + 16*nt];
  int b = blockIdx.x / NBB, blk = blockIdx.x % NBB;
  unsigned short* Tw = T1[wid];
  unsigned short* Vw = T2[wid];
  floatx4 zz = {0.f, 0.f, 0.f, 0.f};
  floatx4 kvacc[4] = {zz, zz, zz, zz};
  float ksp[4] = {0.f,0.f,0.f,0.f};
  float vsp[4] = {0.f,0.f,0.f,0.f};
  const short8v z8 = {0,0,0,0,0,0,0,0};
  for (int st = blk*4 + wid; st < 1250; st += NBB*4){
    size_t gr = (size_t)b*VDIM + (size_t)st*16;
    #pragma unroll
    for (int it = 0; it < 4; it++){
      int rl = it*4 + lg;
      size_t gi = (gr + rl)*64 + 4*lr;
      float4 xq4 = ldf4(Xqk, gi);
      float4 xv4 = ldf4(Xv, gi);
      int si = swz(rl, 4*lr);
      ushort4 tq, tv;
      tq.x = f2b(xq4.x); tq.y = f2b(xq4.y); tq.z = f2b(xq4.z); tq.w = f2b(xq4.w);
      tv.x = f2b(xv4.x); tv.y = f2b(xv4.y); tv.z = f2b(xv4.z); tv.w = f2b(xv4.w);
      *(ushort4*)&Tw[si] = tq;
      *(ushort4*)&Vw[si] = tv;
      vsp[0] += xv4.x; vsp[1] += xv4.y; vsp[2] += xv4.z; vsp[3] += xv4.w;
    }
    wsync();
    short8v a0 = *(const short8v*)&Tw[swz(lr, lg*8)];
    short8v a1 = *(const short8v*)&Tw[swz(lr, 32 + lg*8)];
    // k-projection + head norm -> kn (C-layout regs), store kn_t to T1
    float kn[4][4];
    #pragma unroll
    for (int nt = 0; nt < 4; nt++){
      floatx4 acc = zz;
      acc = __builtin_amdgcn_mfma_f32_16x16x32_bf16(a0, wkf[nt][0], acc, 0, 0, 0);
      acc = __builtin_amdgcn_mfma_f32_16x16x32_bf16(a1, wkf[nt][1], acc, 0, 0, 0);
      #pragma unroll
      for (int q = 0; q < 4; q++) kn[nt][q] = acc[q] + bk[nt];
    }
    #pragma unroll
    for (int nt = 0; nt < 4; nt++){
      float n0 = kn[nt][0]*kn[nt][0], n1 = kn[nt][1]*kn[nt][1];
      float n2 = kn[nt][2]*kn[nt][2], n3 = kn[nt][3]*kn[nt][3];
      #pragma unroll
      for (int o = 1; o < 16; o <<= 1){
        n0 += __shfl_xor(n0, o, 64); n1 += __shfl_xor(n1, o, 64);
        n2 += __shfl_xor(n2, o, 64); n3 += __shfl_xor(n3, o, 64);
      }
      kn[nt][0] /= fmaxf(sqrtf(n0), 1e-12f);
      kn[nt][1] /= fmaxf(sqrtf(n1), 1e-12f);
      kn[nt][2] /= fmaxf(sqrtf(n2), 1e-12f);
      kn[nt][3] /= fmaxf(sqrtf(n3), 1e-12f);
      ksp[nt] += kn[nt][0] + kn[nt][1] + kn[nt][2] + kn[nt][3];
    }
    wsync();   // a0/a1 consumed; safe to overwrite T1 with kn_t
    #pragma unroll
    for (int nt = 0; nt < 4; nt++){
      int c = lr + 16*nt;
      #pragma unroll
      for (int q = 0; q < 4; q++)
        Tw[c*16 + lg*4 + q] = f2b(kn[nt][q]);
    }
    wsync();
    // kv += kn^T (A) x vx (B), per head, K=16 rows zero-padded to 32
    #pragma unroll
    for (int nt = 0; nt < 4; nt++){
      short8v af = z8, bf = z8;
      if (lg < 2){
        af = *(const short8v*)&Tw[(nt*16 + lr)*16 + lg*8];
        #pragma unroll
        for (int j = 0; j < 8; j++)
          bf[j] = (short)Vw[swz(lg*8 + j, nt*16 + lr)];
      }
      kvacc[nt] = __builtin_amdgcn_mfma_f32_16x16x32_bf16(af, bf, kvacc[nt], 0, 0, 0);
    }
    wsync();   // LDS reads done before next stripe overwrites tiles
  }
  // write per-wave partials
  float* rw = red + wid*1536;
  #pragma unroll
  for (int nt = 0; nt < 4; nt++){
    #pragma unroll
    for (int q = 0; q < 4; q++)
      rw[(nt*16 + lg*4 + q)*16 + lr] = kvacc[nt][q];
    rw[1024 + lg*64 + lr + 16*nt] = ksp[nt];
  }
  #pragma unroll
  for (int m = 0; m < 4; m++)
    rw[1280 + lg*64 + 4*lr + m] = vsp[m];
  __syncthreads();
  float* P = partial + (size_t)blockIdx.x*1152;
  for (int j = tid; j < 1152; j += 256){
    float s = 0.f;
    if (j < 1024){
      #pragma unroll
      for (int wv = 0; wv < 4; wv++) s += red[wv*1536 + j];
    } else if (j < 1088){
      int c = j - 1024;
      #pragma unroll
      for (int wv = 0; wv < 4; wv++)
        #pragma unroll
        for (int gg = 0; gg < 4; gg++) s += red[wv*1536 + 1024 + gg*64 + c];
    } else {
      int c = j - 1088;
      #pragma unroll
      for (int wv = 0; wv < 4; wv++)
        #pragma unroll
        for (int gg = 0; gg < 4; gg++) s += red[wv*1536 + 1280 + gg*64 + c];
    }
    P[j] = s;
  }
}

// ---- reduce kvred partials ----
__global__ void qkred_kernel(const float* __restrict__ partial,
                             float* __restrict__ kvs, float* __restrict__ ksum, float* __restrict__ vsum){
  int b = blockIdx.x / 5, ch = blockIdx.x % 5;
  int j = ch*256 + threadIdx.x;
  if (j >= 1152) return;
  const float* P = partial + (size_t)b*NBB*1152;
  float s = 0.f;
  for (int t = 0; t < NBB; t++) s += P[(size_t)t*1152 + j];
  if (j < 1024)      kvs[b*1024 + j] = s;
  else if (j < 1088) ksum[b*64 + (j-1024)] = s;
  else               vsum[b*64 + (j-1088)] = s;
}

// ---- attention finalize (MFMA): q-proj + head-norm + per-head num/den MFMAs + LN ----
template<typename T>
__global__ __launch_bounds__(256) void attn_mfma_kernel(
    const float* __restrict__ x, T* __restrict__ A, const T* __restrict__ Xv,
    const float* __restrict__ kvs, const float* __restrict__ ksum, const float* __restrict__ vsum,
    const float* __restrict__ w, const float* __restrict__ bias,
    const float* __restrict__ g, const float* __restrict__ bb){
  __shared__ float kvss[4096];
  __shared__ float kss[256], vss[256];
  __shared__ unsigned short Ql[4][1024];   // Xqk stage then qn tile
  int tid = threadIdx.x, lane = tid & 63, wid = tid >> 6;
  int lr = lane & 15, lg = lane >> 4;
  short8v wqf[4][2];
  #pragma unroll
  for (int nt = 0; nt < 4; nt++){
    int col = lr + 16*nt;                    // q-half of fc_to_qk
    #pragma unroll
    for (int ks = 0; ks < 2; ks++){
      const float* p = w + col*64 + ks*32 + lg*8;
      short8v f;
      #pragma unroll
      for (int j = 0; j < 8; j++) f[j] = (short)f2b(p[j]);
      wqf[nt][ks] = f;
    }
  }
  float bq[4], gl[4], bl[4];
  #pragma unroll
  for (int nt = 0; nt < 4; nt++){
    int c = lr + 16*nt;
    bq[nt] = bias[c]; gl[nt] = g[c]; bl[nt] = bb[c];
  }
  for (int i = tid; i < 4096; i += 256) kvss[i] = kvs[i];
  kss[tid] = ksum[tid];
  vss[tid] = vsum[tid];
  __syncthreads();
  unsigned short* Qw = Ql[wid];
  floatx4 zz = {0.f, 0.f, 0.f, 0.f};
  const short8v z8 = {0,0,0,0,0,0,0,0};
  int tile = blockIdx.x;
  int row0 = tile*64 + wid*16;
  int b = row0 / VDIM;                       // wave-uniform (16 | 20000)
  // stage Xqk tile
  #pragma unroll
  for (int it = 0; it < 4; it++){
    int rl = it*4 + lg;
    size_t gi = (size_t)(row0 + rl)*64 + 4*lr;
    float4 a4 = ldf4(A, gi);
    ushort4 tt;
    tt.x = f2b(a4.x); tt.y = f2b(a4.y); tt.z = f2b(a4.z); tt.w = f2b(a4.w);
    *(ushort4*)&Qw[swz(rl, 4*lr)] = tt;
  }
  wsync();
  short8v a0 = *(const short8v*)&Qw[swz(lr, lg*8)];
  short8v a1 = *(const short8v*)&Qw[swz(lr, 32 + lg*8)];
  // q projection + head norm
  float qn[4][4];
  #pragma unroll
  for (int nt = 0; nt < 4; nt++){
    floatx4 acc = zz;
    acc = __builtin_amdgcn_mfma_f32_16x16x32_bf16(a0, wqf[nt][0], acc, 0, 0, 0);
    acc = __builtin_amdgcn_mfma_f32_16x16x32_bf16(a1, wqf[nt][1], acc, 0, 0, 0);
    #pragma unroll
    for (int q = 0; q < 4; q++) qn[nt][q] = acc[q] + bq[nt];
  }
  #pragma unroll
  for (int nt = 0; nt < 4; nt++){
    float n0 = qn[nt][0]*qn[nt][0], n1 = qn[nt][1]*qn[nt][1];
    float n2 = qn[nt][2]*qn[nt][2], n3 = qn[nt][3]*qn[nt][3];
    #pragma unroll
    for (int o = 1; o < 16; o <<= 1){
      n0 += __shfl_xor(n0, o, 64); n1 += __shfl_xor(n1, o, 64);
      n2 += __shfl_xor(n2, o, 64); n3 += __shfl_xor(n3, o, 64);
    }
    qn[nt][0] /= fmaxf(sqrtf(n0), 1e-12f);
    qn[nt][1] /= fmaxf(sqrtf(n1), 1e-12f);
    qn[nt][2] /= fmaxf(sqrtf(n2), 1e-12f);
    qn[nt][3] /= fmaxf(sqrtf(n3), 1e-12f);
  }
  wsync();   // a0/a1 consumed; overwrite Q tile with qn (swizzled [16][64])
  #pragma unroll
  for (int nt = 0; nt < 4; nt++){
    #pragma unroll
    for (int q = 0; q < 4; q++)
      Qw[swz(lg*4 + q, lr + 16*nt)] = f2b(qn[nt][q]);
  }
  wsync();
  // per-head attention: num/den via zero-padded 16x16x32 MFMAs
  float y[4][4];
  float s[4] = {0.f,0.f,0.f,0.f}, ss[4] = {0.f,0.f,0.f,0.f};
  #pragma unroll
  for (int nt = 0; nt < 4; nt++){
    short8v af = z8, bn = z8, bd = z8;
    if (lg < 2){
      af = *(const short8v*)&Qw[swz(lr, nt*16 + lg*8)];
      #pragma unroll
      for (int j = 0; j < 8; j++){
        bn[j] = (short)f2b(kvss[b*1024 + (nt*16 + lg*8 + j)*16 + lr]);
        bd[j] = (short)f2b(kss[b*64 + nt*16 + lg*8 + j]);
      }
    }
    int c = lr + 16*nt;
    float vsb = vss[b*64 + c];
    floatx4 numc, denc;
    #pragma unroll
    for (int q = 0; q < 4; q++){
      float vv = ldf(Xv, (size_t)(row0 + lg*4 + q)*64 + c);
      numc[q] = vsb + vv*(float)VDIM;
      denc[q] = 2.0f*(float)VDIM;
    }
    numc = __builtin_amdgcn_mfma_f32_16x16x32_bf16(af, bn, numc, 0, 0, 0);
    denc = __builtin_amdgcn_mfma_f32_16x16x32_bf16(af, bd, denc, 0, 0, 0);
    #pragma unroll
    for (int q = 0; q < 4; q++){
      float xv = x[(size_t)(row0 + lg*4 + q)*64 + c];
      float v = xv + numc[q]/denc[q];
      y[nt][q] = v; s[q] += v; ss[q] += v*v;
    }
  }
  #pragma unroll
  for (int o = 1; o < 16; o <<= 1){
    #pragma unroll
    for (int q = 0; q < 4; q++){
      s[q] += __shfl_xor(s[q], o, 64);
      ss[q] += __shfl_xor(ss[q], o, 64);
    }
  }
  #pragma unroll
  for (int q = 0; q < 4; q++){
    float mu = s[q]*(1.f/64.f);
    float var = fmaxf(ss[q]*(1.f/64.f) - mu*mu, 0.f);
    float rs = rsqrtf(var + LN_EPS);
    #pragma unroll
    for (int nt = 0; nt < 4; nt++){
      int c = lr + 16*nt;
      stf(A, (size_t)(row0 + lg*4 + q)*64 + c, (y[nt][q] - mu)*rs*gl[nt] + bl[nt]);
    }
  }
}

// ================= host side =================
static const int DICT_SIZES[42] = {
  5120000,256,256,80000,262144,4096,4160,64,4096,64,
  8192,64,4096,64,8192,128,8192,128,8192,128,
  128,128,128,524288,8192,8192,128,8192,128,128,
  128,128,4096,64,4096,64,64,64,64,64,
  4,600000};

template<typename T>
static void run_pipeline(const float* const* N, const int* hi,
                         const int* row_ptr, const int2* pk,
                         float* qk_z, float* zr, float* kvs, float* part,
                         T* Obuf, T* A, T* B, float* outp, hipStream_t stream){
  float* ksum = kvs + 4096;
  float* vsum = kvs + 4352;

  zcalc_kernel<<<192, 256, 0, stream>>>(N[1], N[4], N[5], N[23], N[24], qk_z, zr);

  initqk_mfma_kernel<T><<<NTILE, 256, 0, stream>>>(N[0], N[3], N[6], N[7], N[8], N[9], A);
  for (int i = 0; i < 2; i++){
    rspmm_gather<T><<<VDIM/8, 256, 0, stream>>>(row_ptr, pk, qk_z, A, Obuf);
    loop_mfma_kernel<T><<<NTILE, 256, 0, stream>>>(Obuf, A, N[20] + i*64, N[16] + i*4096, N[17] + i*64,
                                                   N[18] + i*4096, N[19] + i*64, N[21] + i*64, N[22] + i*64);
  }
  initv_mfma_kernel<T><<<NTILE, 256, 0, stream>>>(N[0], hi, N[10], N[11], N[12], N[13], B);
  for (int i = 0; i < 2; i++){
    rspmm_gather<T><<<VDIM/8, 256, 0, stream>>>(row_ptr, pk, zr + i*16384, B, Obuf);
    loop_mfma_kernel<T><<<NTILE, 256, 0, stream>>>(Obuf, B, N[29] + i*64, N[25] + i*4096, N[26] + i*64,
                                                   N[27] + i*4096, N[28] + i*64, N[30] + i*64, N[31] + i*64);
  }
  kvred_mfma_kernel<T><<<BDIM*NBB, 256, 0, stream>>>(A, B, N[14], N[15], part);
  qkred_kernel<<<20, 256, 0, stream>>>(part, kvs, ksum, vsum);
  attn_mfma_kernel<T><<<NTILE, 256, 0, stream>>>(N[0], A, B, kvs, ksum, vsum, N[14], N[15], N[36], N[37]);
  final_mfma_kernel<T><<<NTILE, 256, 0, stream>>>(A, N[32], N[33], N[34], N[35], N[38], N[39], outp);
}

extern "C" void kernel_launch(void* const* d_in, const int* in_sizes, int n_in,
                              void* d_out, int out_size, void* d_ws, size_t ws_size,
                              hipStream_t stream){
  float* outp = (float*)d_out;
  const int GOUT = (out_size + 255) / 256;

  if (n_in != 42){
    fill_kernel<<<GOUT, 256, 0, stream>>>(outp, 2000.0f + (float)n_in, out_size);
    return;
  }
  auto sz_ok = [&](int s, int e)->bool{
    if (s == e) return true;
    if ((e == 4 || e == 600000) && s == 2*e) return true;
    return false;
  };
  int bad = -1;
  for (int i = 0; i < 42 && bad < 0; i++)
    if (!sz_ok(in_sizes[i], DICT_SIZES[i])) bad = i;
  if (bad >= 0){
    fill_kernel<<<GOUT, 256, 0, stream>>>(outp, 1000.0f + (float)bad, out_size);
    return;
  }

  const float* N[40];
  for (int i = 0; i < 40; i++) N[i] = (const float*)d_in[i];
  const int* hi_raw = (const int*)d_in[40];
  const int* ei_raw = (const int*)d_in[41];

  char* p = (char*)d_ws;
  auto alloc = [&](size_t bytes)->char*{ char* r = p; p += (bytes + 255) / 256 * 256; return r; };
  int* ei      = (int*)alloc((size_t)3*EDIM*4);
  int* hi      = (int*)alloc(256);
  int* eflag   = (int*)alloc(256);
  int* counts  = (int*)alloc((VDIM+1)*4);
  int* row_ptr = (int*)alloc((VDIM+1)*4);
  int* cursor  = (int*)alloc((VDIM+1)*4);
  int2* pk     = (int2*)alloc((size_t)EDIM*8);
  float* qk_z  = (float*)alloc(16384u*4);
  float* zr    = (float*)alloc(32768u*4);
  float* kvs   = (float*)alloc(4608u*4);
  float* part  = (float*)alloc((size_t)BDIM*NBB*1152*4);
  size_t fixed = (size_t)(p - (char*)d_ws);
  bool f32ok = ws_size >= fixed + 3*(size_t)BV*64*4 + 1024;

  detect_kernel<<<1, 256, 0, stream>>>(ei_raw, eflag);
  prep_idx_kernel<<<(3*EDIM+255)/256, 256, 0, stream>>>(ei_raw, hi_raw, eflag, ei, hi);
  zero_kernel<<<(VDIM+256)/256, 256, 0, stream>>>(counts);
  count_kernel<<<(EDIM+255)/256, 256, 0, stream>>>(ei, counts);
  scan_kernel<<<1, 256, 0, stream>>>(counts, row_ptr, cursor);
  scatter_kernel<<<(EDIM+255)/256, 256, 0, stream>>>(ei, cursor, pk);

  if (f32ok){
    float* Obuf = (float*)alloc((size_t)BV*64*4);
    float* A    = (float*)alloc((size_t)BV*64*4);
    float* B    = (float*)alloc((size_t)BV*64*4);
    run_pipeline<float>(N, hi, row_ptr, pk, qk_z, zr, kvs, part, Obuf, A, B, outp, stream);
  } else {
    bf16* Obuf = (bf16*)alloc((size_t)BV*64*2);
    bf16* A    = (bf16*)alloc((size_t)BV*64*2);
    bf16* B    = (bf16*)alloc((size_t)BV*64*2);
    run_pipeline<bf16>(N, hi, row_ptr, pk, qk_z, zr, kvs, part, Obuf, A, B, outp, stream);
  }
}